// Round 9
// baseline (524.207 us; speedup 1.0000x reference)
//
#include <hip/hip_runtime.h>
#include <hip/hip_bf16.h>

typedef __attribute__((ext_vector_type(8))) short bf16x8;
typedef __attribute__((ext_vector_type(4))) float f32x4;
typedef __attribute__((ext_vector_type(4))) unsigned short us4;

#define DEV __device__ __forceinline__

constexpr int Bc = 8, Tc = 1024, HIDc = 2048, Hc = 16, Dc = 128;
constexpr int ROWSc = Bc * Tc;  // 8192

DEV unsigned short f2bfb(float x) {
  union { float f; unsigned u; } v; v.f = x;
  unsigned r = v.u + 0x7fffu + ((v.u >> 16) & 1u);  // round-to-nearest-even
  return (unsigned short)(r >> 16);
}
DEV unsigned short f2bfb_fast(float x) {  // round-half-up (2 VALU ops)
  union { float f; unsigned u; } v; v.f = x;
  return (unsigned short)((v.u + 0x8000u) >> 16);
}
DEV float bfb2f(unsigned short b) {
  union { unsigned u; float f; } v; v.u = ((unsigned)b) << 16; return v.f;
}
DEV float fexp2(float x) { return __builtin_amdgcn_exp2f(x); }  // native v_exp_f32

// async global->LDS, 16B per lane; LDS dest = wave-uniform base + lane*16
DEV void gload16(const void* g, void* l) {
  __builtin_amdgcn_global_load_lds(
      (const __attribute__((address_space(1))) unsigned int*)g,
      (__attribute__((address_space(3))) unsigned int*)l, 16, 0, 0);
}

// ---------------- elementwise prep ----------------

__global__ void k_blend(const float* __restrict__ cg, const float* __restrict__ sg,
                        const float* __restrict__ cl, const float* __restrict__ sl,
                        const float* __restrict__ gl,
                        float* __restrict__ cosb, float* __restrict__ sinb) {
  int u = blockIdx.x * 256 + threadIdx.x;
  if (u >= Tc * 64) return;
  float a = 1.0f / (1.0f + __expf(-gl[0]));
  cosb[u] = cg[u] * a + cl[u] * (1.0f - a);
  sinb[u] = sg[u] * a + sl[u] * (1.0f - a);
}

__global__ void k_zero(unsigned short* __restrict__ p, int n) {
  int i = blockIdx.x * 256 + threadIdx.x;
  if (i < n) p[i] = 0;
}

// transpose fp32 [R][C] -> bf16 [C][R]; R,C multiples of 32
__global__ __launch_bounds__(256) void k_transpose(const float* __restrict__ in,
                                                   unsigned short* __restrict__ out,
                                                   int R, int C) {
  __shared__ float tile[32][33];
  int tx = threadIdx.x & 31, ty = threadIdx.x >> 5;
  int r0 = blockIdx.y * 32, c0 = blockIdx.x * 32;
#pragma unroll
  for (int i = 0; i < 4; i++)
    tile[ty + i * 8][tx] = in[(size_t)(r0 + ty + i * 8) * C + c0 + tx];
  __syncthreads();
#pragma unroll
  for (int i = 0; i < 4; i++) {
    int rr = ty + i * 8;
    out[(size_t)(c0 + rr) * R + r0 + tx] = f2bfb(tile[tx][rr]);
  }
}

// ---------------- GEMM1: A1[8192,256] = h_fp32 @ W1t^T, fused f32->bf16 ----------------

__global__ __launch_bounds__(256) void k_gemm1(const float* __restrict__ A,
                                               const unsigned short* __restrict__ Bt,
                                               float* __restrict__ C) {
  constexpr int K = 2048, N = 256;
  __shared__ __align__(16) unsigned short As[64 * 32];
  __shared__ __align__(16) unsigned short Bs[128 * 32];
  int lin = blockIdx.x;
  int wg = (lin & 7) * 32 + (lin >> 3);
  int m0 = (wg >> 1) * 64, n0 = (wg & 1) * 128;
  int tid = threadIdx.x, lane = tid & 63, wc = tid >> 6;
  int ar = tid >> 2, akc = (tid & 3) * 8;
  const float* Ag = A + (size_t)(m0 + ar) * K + akc;
  const unsigned short* Bg0 = Bt + (size_t)(n0 + ar) * K + akc;
  const unsigned short* Bg1 = Bt + (size_t)(n0 + 64 + ar) * K + akc;
  unsigned short* Bsl0 = &Bs[tid * 8];
  unsigned short* Bsl1 = &Bs[2048 + tid * 8];
  f32x4 acc[4][2];
  f32x4 zz = {0.f, 0.f, 0.f, 0.f};
#pragma unroll
  for (int m = 0; m < 4; m++)
#pragma unroll
    for (int n = 0; n < 2; n++) acc[m][n] = zz;
  int fr = lane & 15, fk = (lane >> 4) * 8;
  for (int kt = 0; kt < K; kt += 32) {
    float4 a0 = *(const float4*)(Ag + kt);
    float4 a1 = *(const float4*)(Ag + kt + 4);
    __syncthreads();  // previous iter's frag reads done
    gload16(Bg0 + kt, Bsl0);
    gload16(Bg1 + kt, Bsl1);
    us4 c0 = { f2bfb(a0.x), f2bfb(a0.y), f2bfb(a0.z), f2bfb(a0.w) };
    us4 c1 = { f2bfb(a1.x), f2bfb(a1.y), f2bfb(a1.z), f2bfb(a1.w) };
    *(us4*)&As[ar * 32 + akc] = c0;
    *(us4*)&As[ar * 32 + akc + 4] = c1;
    __syncthreads();  // staged (drains vm+lgkm)
    bf16x8 af[4], bfv[2];
#pragma unroll
    for (int i = 0; i < 4; i++)
      af[i] = *(const bf16x8*)&As[(i * 16 + fr) * 32 + fk];
#pragma unroll
    for (int i = 0; i < 2; i++)
      bfv[i] = *(const bf16x8*)&Bs[(wc * 32 + i * 16 + fr) * 32 + fk];
    __builtin_amdgcn_s_setprio(1);
#pragma unroll
    for (int m = 0; m < 4; m++)
#pragma unroll
      for (int n = 0; n < 2; n++)
        acc[m][n] = __builtin_amdgcn_mfma_f32_16x16x32_bf16(af[m], bfv[n], acc[m][n], 0, 0, 0);
    __builtin_amdgcn_s_setprio(0);
  }
  int gg = lane >> 4;
#pragma unroll
  for (int m = 0; m < 4; m++)
#pragma unroll
    for (int n = 0; n < 2; n++)
#pragma unroll
      for (int r = 0; r < 4; r++) {
        size_t row = (size_t)m0 + m * 16 + gg * 4 + r;
        size_t col = (size_t)n0 + wc * 32 + n * 16 + fr;
        C[row * N + col] = acc[m][n][r];
      }
}

// ---------------- MFMA GEMM (m97 structure): C = A @ Bt^T ----------------
// 128x128 tile, BK=32, 4 waves, global_load_lds width-16 staging.
// 1D grid with XCD-contiguous swizzle (grid%8==0).

template <int OUTB>
__global__ __launch_bounds__(256) void k_gemm(const unsigned short* __restrict__ A,
                                              const unsigned short* __restrict__ Bt,
                                              void* __restrict__ outp,
                                              int M, int N, int K, int nx) {
  __shared__ __align__(16) unsigned short As[4096];  // [128][32]
  __shared__ __align__(16) unsigned short Bs[4096];
  int lin = blockIdx.x;
  int qq = gridDim.x >> 3;
  int wg = (lin & 7) * qq + (lin >> 3);
  int m0 = (wg / nx) * 128, n0 = (wg % nx) * 128;
  int tid = threadIdx.x;
  int lane = tid & 63;
  int wave = tid >> 6;
  int wr = wave >> 1, wc = wave & 1;
  int srow = tid >> 2;
  int skc = (tid & 3) * 8;
  const unsigned short* Ag0 = A + (size_t)(m0 + srow) * K + skc;
  const unsigned short* Ag1 = A + (size_t)(m0 + 64 + srow) * K + skc;
  const unsigned short* Bg0 = Bt + (size_t)(n0 + srow) * K + skc;
  const unsigned short* Bg1 = Bt + (size_t)(n0 + 64 + srow) * K + skc;
  unsigned short* Asl0 = &As[tid * 8];
  unsigned short* Asl1 = &As[2048 + tid * 8];
  unsigned short* Bsl0 = &Bs[tid * 8];
  unsigned short* Bsl1 = &Bs[2048 + tid * 8];
  f32x4 acc[4][4];
  f32x4 zz = {0.f, 0.f, 0.f, 0.f};
#pragma unroll
  for (int m = 0; m < 4; m++)
#pragma unroll
    for (int n = 0; n < 4; n++) acc[m][n] = zz;
  int fr = lane & 15, fk = (lane >> 4) * 8;
  for (int kt = 0; kt < K; kt += 32) {
    __syncthreads();  // previous iter's frag reads done
    gload16(Ag0 + kt, Asl0);
    gload16(Ag1 + kt, Asl1);
    gload16(Bg0 + kt, Bsl0);
    gload16(Bg1 + kt, Bsl1);
    __syncthreads();  // compiler drains vmcnt before barrier
    bf16x8 af[4], bfv[4];
#pragma unroll
    for (int i = 0; i < 4; i++)
      af[i] = *(const bf16x8*)&As[(wr * 64 + i * 16 + fr) * 32 + fk];
#pragma unroll
    for (int i = 0; i < 4; i++)
      bfv[i] = *(const bf16x8*)&Bs[(wc * 64 + i * 16 + fr) * 32 + fk];
    __builtin_amdgcn_s_setprio(1);
#pragma unroll
    for (int m = 0; m < 4; m++)
#pragma unroll
      for (int n = 0; n < 4; n++)
        acc[m][n] = __builtin_amdgcn_mfma_f32_16x16x32_bf16(af[m], bfv[n], acc[m][n], 0, 0, 0);
    __builtin_amdgcn_s_setprio(0);
  }
  int gg = lane >> 4;
#pragma unroll
  for (int m = 0; m < 4; m++)
#pragma unroll
    for (int n = 0; n < 4; n++)
#pragma unroll
      for (int r = 0; r < 4; r++) {
        size_t row = (size_t)m0 + wr * 64 + m * 16 + gg * 4 + r;
        size_t col = (size_t)n0 + wc * 64 + n * 16 + fr;
        if (OUTB)
          ((unsigned short*)outp)[row * N + col] = f2bfb(acc[m][n][r]);
        else
          ((float*)outp)[row * N + col] = acc[m][n][r];
      }
}

// ---------------- GEMM2a + fused RoPE-Q epilogue ----------------
// qfinal = rope_mix(Qn @ Wqbt^T + bqb) * SCLQ, written directly to Qf.
// Tile 128x128: col tile == one head (N=2048, heads of 128). Tile staged as
// biased bf16 in LDS (chunk-swizzled), then rope pairs (d, d+64) read in-block.

__global__ __launch_bounds__(256) void k_gemm2q(const unsigned short* __restrict__ A,
                                                const unsigned short* __restrict__ Bt,
                                                const float* __restrict__ bqb,
                                                const float* __restrict__ cosb,
                                                const float* __restrict__ sinb,
                                                const float* __restrict__ nl,
                                                unsigned short* __restrict__ Qf) {
  constexpr int K = 128, N = 2048;
  __shared__ __align__(16) unsigned short As[4096];
  __shared__ __align__(16) unsigned short Bs[4096];
  __shared__ __align__(16) unsigned short Qt[128 * 128];  // 32 KB
  int lin = blockIdx.x;
  int wg = (lin & 7) * 128 + (lin >> 3);
  int m0 = (wg >> 4) * 128, n0 = (wg & 15) * 128;
  int h = n0 >> 7;
  int b = m0 >> 10, t0 = m0 & 1023;
  int tid = threadIdx.x;
  int lane = tid & 63;
  int wave = tid >> 6;
  int wr = wave >> 1, wc = wave & 1;
  int srow = tid >> 2;
  int skc = (tid & 3) * 8;
  const unsigned short* Ag0 = A + (size_t)(m0 + srow) * K + skc;
  const unsigned short* Ag1 = A + (size_t)(m0 + 64 + srow) * K + skc;
  const unsigned short* Bg0 = Bt + (size_t)(n0 + srow) * K + skc;
  const unsigned short* Bg1 = Bt + (size_t)(n0 + 64 + srow) * K + skc;
  unsigned short* Asl0 = &As[tid * 8];
  unsigned short* Asl1 = &As[2048 + tid * 8];
  unsigned short* Bsl0 = &Bs[tid * 8];
  unsigned short* Bsl1 = &Bs[2048 + tid * 8];
  f32x4 acc[4][4];
  f32x4 zz = {0.f, 0.f, 0.f, 0.f};
#pragma unroll
  for (int m = 0; m < 4; m++)
#pragma unroll
    for (int n = 0; n < 4; n++) acc[m][n] = zz;
  int fr = lane & 15, fk = (lane >> 4) * 8;
  for (int kt = 0; kt < K; kt += 32) {
    __syncthreads();
    gload16(Ag0 + kt, Asl0);
    gload16(Ag1 + kt, Asl1);
    gload16(Bg0 + kt, Bsl0);
    gload16(Bg1 + kt, Bsl1);
    __syncthreads();
    bf16x8 af[4], bfv[4];
#pragma unroll
    for (int i = 0; i < 4; i++)
      af[i] = *(const bf16x8*)&As[(wr * 64 + i * 16 + fr) * 32 + fk];
#pragma unroll
    for (int i = 0; i < 4; i++)
      bfv[i] = *(const bf16x8*)&Bs[(wc * 64 + i * 16 + fr) * 32 + fk];
    __builtin_amdgcn_s_setprio(1);
#pragma unroll
    for (int m = 0; m < 4; m++)
#pragma unroll
      for (int n = 0; n < 4; n++)
        acc[m][n] = __builtin_amdgcn_mfma_f32_16x16x32_bf16(af[m], bfv[n], acc[m][n], 0, 0, 0);
    __builtin_amdgcn_s_setprio(0);
  }
  // stage biased bf16 tile into LDS (chunk-swizzled rows)
  int gg = lane >> 4;
#pragma unroll
  for (int n = 0; n < 4; n++) {
    int col = wc * 64 + n * 16 + fr;
    float bias = bqb[h * 128 + col];
    int ch = col >> 3, wi = col & 7;
#pragma unroll
    for (int m = 0; m < 4; m++)
#pragma unroll
      for (int r = 0; r < 4; r++) {
        int lrow = wr * 64 + m * 16 + gg * 4 + r;
        Qt[lrow * 128 + ((ch ^ (lrow & 7)) << 3) + wi] = f2bfb(acc[m][n][r] + bias);
      }
  }
  __syncthreads();
  // rope + nope mix + SCLQ, vectorized pairs (d, d+64)
  const float SCLQ = 0.08838834764831845f * 1.4426950408889634f;
  float na = 1.0f / (1.0f + __expf(-nl[0]));
  float nb = 1.0f - na;
#pragma unroll
  for (int it = 0; it < 4; it++) {
    int task = it * 256 + tid;
    int lrow = task >> 3, cp = task & 7;
    int t = t0 + lrow;
    bf16x8 v1 = *(const bf16x8*)&Qt[lrow * 128 + ((cp ^ (lrow & 7)) << 3)];
    bf16x8 v2 = *(const bf16x8*)&Qt[lrow * 128 + (((cp + 8) ^ (lrow & 7)) << 3)];
    float4 cA = *(const float4*)(cosb + t * 64 + cp * 8);
    float4 cB = *(const float4*)(cosb + t * 64 + cp * 8 + 4);
    float4 sA = *(const float4*)(sinb + t * 64 + cp * 8);
    float4 sB = *(const float4*)(sinb + t * 64 + cp * 8 + 4);
    float cv[8] = {cA.x, cA.y, cA.z, cA.w, cB.x, cB.y, cB.z, cB.w};
    float sv[8] = {sA.x, sA.y, sA.z, sA.w, sB.x, sB.y, sB.z, sB.w};
    float f1[8], f2[8];
#pragma unroll
    for (int j = 0; j < 8; j++) {
      float q1 = bfb2f((unsigned short)v1[j]);
      float q2 = bfb2f((unsigned short)v2[j]);
      float p1 = q1 * cv[j] - q2 * sv[j];
      float p2 = q2 * cv[j] + q1 * sv[j];
      f1[j] = (na * q1 + nb * p1) * SCLQ;
      f2[j] = (na * q2 + nb * p2) * SCLQ;
    }
    unsigned short* ob = Qf + ((size_t)(b * Hc + h) * Tc + t) * Dc + cp * 8;
    us4 o0 = {f2bfb(f1[0]), f2bfb(f1[1]), f2bfb(f1[2]), f2bfb(f1[3])};
    us4 o1 = {f2bfb(f1[4]), f2bfb(f1[5]), f2bfb(f1[6]), f2bfb(f1[7])};
    us4 o2 = {f2bfb(f2[0]), f2bfb(f2[1]), f2bfb(f2[2]), f2bfb(f2[3])};
    us4 o3 = {f2bfb(f2[4]), f2bfb(f2[5]), f2bfb(f2[6]), f2bfb(f2[7])};
    *(us4*)(ob) = o0;
    *(us4*)(ob + 4) = o1;
    *(us4*)(ob + 64) = o2;
    *(us4*)(ob + 68) = o3;
  }
}

// ---------------- split RMSNorm (q over 128, kv over 64) ----------------

__global__ __launch_bounds__(256) void k_norm(const float* __restrict__ A1,
                                              const float* __restrict__ bqa,
                                              const float* __restrict__ bkva,
                                              const float* __restrict__ qw,
                                              const float* __restrict__ kvw,
                                              unsigned short* __restrict__ Qn,
                                              unsigned short* __restrict__ Kvn) {
  int wave = threadIdx.x >> 6, lane = threadIdx.x & 63;
  int row = blockIdx.x * 4 + wave;
  const float* a = A1 + (size_t)row * 256;
  float x0 = a[lane] + bqa[lane];
  float x1 = a[64 + lane] + bqa[64 + lane];
  float ss = x0 * x0 + x1 * x1;
#pragma unroll
  for (int off = 1; off < 64; off <<= 1) ss += __shfl_xor(ss, off);
  float sc = rsqrtf(ss * (1.0f / 128.0f) + 1e-6f);
  Qn[(size_t)row * 128 + lane] = f2bfb(x0 * sc * qw[lane]);
  Qn[(size_t)row * 128 + 64 + lane] = f2bfb(x1 * sc * qw[64 + lane]);
  float y = a[128 + lane] + bkva[lane];
  float s2 = y * y;
#pragma unroll
  for (int off = 1; off < 64; off <<= 1) s2 += __shfl_xor(s2, off);
  float sc2 = rsqrtf(s2 * (1.0f / 64.0f) + 1e-6f);
  Kvn[(size_t)row * 64 + lane] = f2bfb(y * sc2 * kvw[lane]);
}

// ---------------- RoPE + nope mix for K/V ----------------

__global__ __launch_bounds__(256) void k_rope_kv(const unsigned short* __restrict__ kvr,
                                                 const float* __restrict__ bkvb,
                                                 const float* __restrict__ cosb,
                                                 const float* __restrict__ sinb,
                                                 const float* __restrict__ nl,
                                                 unsigned short* __restrict__ Kf,
                                                 unsigned short* __restrict__ Vt) {
  int u = blockIdx.x * 256 + threadIdx.x;  // < 8192*64
  int row = u >> 6, d = u & 63;
  int t = row & (Tc - 1), b = row >> 10;
  float na = 1.0f / (1.0f + __expf(-nl[0]));
  const unsigned short* kp = kvr + (size_t)row * 256;
  float k1 = bfb2f(kp[d]) + bkvb[d];
  float k2 = bfb2f(kp[64 + d]) + bkvb[64 + d];
  float v1 = bfb2f(kp[128 + d]) + bkvb[128 + d];
  float v2 = bfb2f(kp[192 + d]) + bkvb[192 + d];
  float cv = cosb[t * 64 + d], sv = sinb[t * 64 + d];
  float p1 = k1 * cv - k2 * sv;
  float p2 = k2 * cv + k1 * sv;
  float f1 = na * k1 + (1.0f - na) * p1;
  float f2 = na * k2 + (1.0f - na) * p2;
  unsigned short* kb = Kf + (size_t)row * Dc;
  kb[d] = f2bfb(f1);
  kb[64 + d] = f2bfb(f2);
  Vt[((size_t)b * Dc + d) * Tc + t] = f2bfb(v1);
  Vt[((size_t)b * Dc + 64 + d) * Tc + t] = f2bfb(v2);
}

// ---------------- flash attention (causal, GQA single KV head) ----------------
// 512 blocks x 512 thr, 2 blocks/CU (64KB LDS, VGPR<=128). One 256-row
// supertile per block (traffic identical to R6's pairing); LPT order (sp=3
// dispatched first); bid&7=b XCD-batch affinity. Single-buffer KV LDS
// (swizzled) + T14 reg prefetch. exp2 softmax, defer-max, per-lane l.

__global__ __launch_bounds__(512, 4) void k_attn(const unsigned short* __restrict__ Qf,
                                                 const unsigned short* __restrict__ Kf,
                                                 const unsigned short* __restrict__ Vt,
                                                 const int* __restrict__ amask,
                                                 unsigned short* __restrict__ O) {
  __shared__ __align__(16) unsigned short Ks[64 * 128];     // [s][d] swizzled
  __shared__ __align__(16) unsigned short Vs[128 * 64];     // [d][s] swizzled
  __shared__ __align__(16) unsigned short Plds[8][32 * 64]; // per-wave P
  __shared__ int s_anyzero;

  int bid = blockIdx.x;
  int b = bid & 7;
  int sp = 3 - ((bid >> 3) & 3);  // LPT: heavy supertiles first
  int h = bid >> 5;
  int tid = threadIdx.x;
  int wave = tid >> 6, lane = tid & 63;
  int g = lane >> 4, c = lane & 15;

  const unsigned short* Kp = Kf + (size_t)b * Tc * Dc;
  const unsigned short* Vp = Vt + (size_t)b * Dc * Tc;
  const int* mp = amask + b * Tc;
  unsigned short* Pw = &Plds[wave][0];
  f32x4 zz = {0.f, 0.f, 0.f, 0.f};

  if (tid == 0) s_anyzero = 0;
  __syncthreads();
  if (mp[tid] == 0 || mp[tid + 512] == 0) s_anyzero = 1;

  // staging geometry: 512 thr; K 64x128 (2 chunks/thr), V 128x64 (2 chunks/thr)
  int kr_ = tid >> 3, kc_ = tid & 7;
  int vr_ = tid >> 2, vc_ = tid & 3;
  int kidx0 = kr_ * 128 + ((kc_ ^ (kr_ & 7)) << 3);
  int kidx1 = kr_ * 128 + (((kc_ + 8) ^ (kr_ & 7)) << 3);
  int vidx0 = vr_ * 64 + ((vc_ ^ (vr_ & 7)) << 3);
  int vidx1 = vr_ * 64 + (((vc_ + 4) ^ (vr_ & 7)) << 3);

  int qw0 = sp * 256 + wave * 32;
  int nt = (sp + 1) * 4;
  const unsigned short* Qp = Qf + ((size_t)(b * Hc + h) * Tc + qw0) * Dc;
  bf16x8 qfr[2][4];
#pragma unroll
  for (int m = 0; m < 2; m++)
#pragma unroll
    for (int ks = 0; ks < 4; ks++)
      qfr[m][ks] = *(const bf16x8*)(Qp + (size_t)(m * 16 + c) * Dc + ks * 32 + g * 8);

  f32x4 Oacc[2][8];
#pragma unroll
  for (int m = 0; m < 2; m++)
#pragma unroll
    for (int i = 0; i < 8; i++) Oacc[m][i] = zz;
  float m_r[2][4], l_r[2][4];
#pragma unroll
  for (int m = 0; m < 2; m++)
#pragma unroll
    for (int r = 0; r < 4; r++) { m_r[m][r] = -1e30f; l_r[m][r] = 0.f; }

  // prefetch tile 0
  bf16x8 krg[2], vrg[2];
  krg[0] = *(const bf16x8*)(Kp + (size_t)kr_ * Dc + kc_ * 8);
  krg[1] = *(const bf16x8*)(Kp + (size_t)kr_ * Dc + kc_ * 8 + 64);
  vrg[0] = *(const bf16x8*)(Vp + (size_t)vr_ * Tc + vc_ * 8);
  vrg[1] = *(const bf16x8*)(Vp + (size_t)vr_ * Tc + vc_ * 8 + 32);
  __syncthreads();  // prescan visible
  bool anyz = (s_anyzero != 0);

  for (int st = 0; st < nt; st++) {
    int s0 = st << 6;
    *(bf16x8*)&Ks[kidx0] = krg[0];
    *(bf16x8*)&Ks[kidx1] = krg[1];
    *(bf16x8*)&Vs[vidx0] = vrg[0];
    *(bf16x8*)&Vs[vidx1] = vrg[1];
    __syncthreads();  // staged
    if (st + 1 < nt) {  // T14: prefetch next tile under compute
      int s1 = s0 + 64;
      krg[0] = *(const bf16x8*)(Kp + (size_t)(s1 + kr_) * Dc + kc_ * 8);
      krg[1] = *(const bf16x8*)(Kp + (size_t)(s1 + kr_) * Dc + kc_ * 8 + 64);
      vrg[0] = *(const bf16x8*)(Vp + (size_t)vr_ * Tc + s1 + vc_ * 8);
      vrg[1] = *(const bf16x8*)(Vp + (size_t)vr_ * Tc + s1 + vc_ * 8 + 32);
    }
    if (s0 <= qw0 + 31) {  // wave has unmasked work
      // ---- QK^T (exp2 domain, scale pre-folded into Q)
      f32x4 S[2][4];
#pragma unroll
      for (int m = 0; m < 2; m++)
#pragma unroll
        for (int j = 0; j < 4; j++) S[m][j] = zz;
      __builtin_amdgcn_s_setprio(1);
#pragma unroll
      for (int ks = 0; ks < 4; ks++)
#pragma unroll
        for (int j = 0; j < 4; j++) {
          bf16x8 kfr = *(const bf16x8*)&Ks[(j * 16 + c) * 128 + (((ks * 4 + g) ^ (c & 7)) << 3)];
          S[0][j] = __builtin_amdgcn_mfma_f32_16x16x32_bf16(qfr[0][ks], kfr, S[0][j], 0, 0, 0);
          S[1][j] = __builtin_amdgcn_mfma_f32_16x16x32_bf16(qfr[1][ks], kfr, S[1][j], 0, 0, 0);
        }
      __builtin_amdgcn_s_setprio(0);

      if (anyz) {
#pragma unroll
        for (int j = 0; j < 4; j++) {
          float madd = (mp[s0 + j * 16 + c] == 0) ? -2e9f : 0.0f;
#pragma unroll
          for (int m = 0; m < 2; m++)
#pragma unroll
            for (int r = 0; r < 4; r++) S[m][j][r] += madd;
        }
      }
      if (s0 + 63 > qw0) {  // causal edge
#pragma unroll
        for (int j = 0; j < 4; j++) {
          int s = s0 + j * 16 + c;
#pragma unroll
          for (int m = 0; m < 2; m++)
#pragma unroll
            for (int r = 0; r < 4; r++)
              if (s > qw0 + m * 16 + g * 4 + r) S[m][j][r] = -1e30f;
        }
      }

      // ---- row max, defer-max update (T13)
      float vmax[2][4];
#pragma unroll
      for (int m = 0; m < 2; m++)
#pragma unroll
        for (int r = 0; r < 4; r++) {
          float v = fmaxf(fmaxf(S[m][0][r], S[m][1][r]), fmaxf(S[m][2][r], S[m][3][r]));
          v = fmaxf(v, __shfl_xor(v, 1));
          v = fmaxf(v, __shfl_xor(v, 2));
          v = fmaxf(v, __shfl_xor(v, 4));
          v = fmaxf(v, __shfl_xor(v, 8));
          vmax[m][r] = v;
        }
      bool upd = false;
#pragma unroll
      for (int m = 0; m < 2; m++)
#pragma unroll
        for (int r = 0; r < 4; r++) upd = upd || (vmax[m][r] > m_r[m][r] + 11.0f);
      if (__any(upd)) {
#pragma unroll
        for (int m = 0; m < 2; m++)
#pragma unroll
          for (int r = 0; r < 4; r++) {
            float mn = fmaxf(m_r[m][r], vmax[m][r]);
            float al = fexp2(m_r[m][r] - mn);
            m_r[m][r] = mn;
            l_r[m][r] *= al;
#pragma unroll
            for (int j2 = 0; j2 < 8; j2++) Oacc[m][j2][r] *= al;
          }
      }

      // ---- exp + per-lane l partial + P -> LDS (swizzled)
#pragma unroll
      for (int m = 0; m < 2; m++)
#pragma unroll
        for (int j = 0; j < 4; j++)
#pragma unroll
          for (int r = 0; r < 4; r++) {
            float e = fexp2(S[m][j][r] - m_r[m][r]);
            l_r[m][r] += e;
            int row = m * 16 + g * 4 + r;
            Pw[row * 64 + (((j * 2 + (c >> 3)) ^ (row & 7)) << 3) + (c & 7)] = f2bfb_fast(e);
          }

      // ---- PV: O += P[32q x 64s] @ V^T
      asm volatile("s_waitcnt lgkmcnt(0)" ::: "memory");
      bf16x8 pfr[2][2];
#pragma unroll
      for (int m = 0; m < 2; m++)
#pragma unroll
        for (int sk = 0; sk < 2; sk++) {
          int row = m * 16 + c;
          pfr[m][sk] = *(const bf16x8*)&Pw[row * 64 + (((sk * 4 + g) ^ (row & 7)) << 3)];
        }
      __builtin_amdgcn_s_setprio(1);
#pragma unroll
      for (int sk = 0; sk < 2; sk++)
#pragma unroll
        for (int j2 = 0; j2 < 8; j2++) {
          int row = j2 * 16 + c;
          bf16x8 vfr = *(const bf16x8*)&Vs[row * 64 + (((sk * 4 + g) ^ (row & 7)) << 3)];
          Oacc[0][j2] = __builtin_amdgcn_mfma_f32_16x16x32_bf16(pfr[0][sk], vfr, Oacc[0][j2], 0, 0, 0);
          Oacc[1][j2] = __builtin_amdgcn_mfma_f32_16x16x32_bf16(pfr[1][sk], vfr, Oacc[1][j2], 0, 0, 0);
        }
      __builtin_amdgcn_s_setprio(0);
    }
    __syncthreads();  // all reads of Ks/Vs done before next-stage writes
  }

  // ---- epilogue: cross-lane l reduce, normalize, direct stores
#pragma unroll
  for (int m = 0; m < 2; m++)
#pragma unroll
    for (int r = 0; r < 4; r++) {
      float v = l_r[m][r];
      v += __shfl_xor(v, 1);
      v += __shfl_xor(v, 2);
      v += __shfl_xor(v, 4);
      v += __shfl_xor(v, 8);
      float inv = 1.0f / v;
      int qr = qw0 + m * 16 + g * 4 + r;
      unsigned short* ob = O + ((size_t)(b * Tc) + qr) * HIDc + h * Dc;
#pragma unroll
      for (int j2 = 0; j2 < 8; j2++) ob[j2 * 16 + c] = f2bfb(Oacc[m][j2][r] * inv);
    }
}

// ---------------- host launch ----------------

extern "C" void kernel_launch(void* const* d_in, const int* in_sizes, int n_in,
                              void* d_out, int out_size, void* d_ws, size_t ws_size,
                              hipStream_t stream) {
  const float* h = (const float*)d_in[0];
  const float* cg = (const float*)d_in[1];
  const float* sg = (const float*)d_in[2];
  const float* cl = (const float*)d_in[3];
  const float* sl = (const float*)d_in[4];
  const float* Wq_a = (const float*)d_in[5];
  const float* bq_a = (const float*)d_in[6];
  const float* Wq_b = (const float*)d_in[7];
  const float* bq_b = (const float*)d_in[8];
  const float* Wkv_a = (const float*)d_in[9];
  const float* bkv_a = (const float*)d_in[10];
  const float* Wkv_b = (const float*)d_in[11];
  const float* bkv_b = (const float*)d_in[12];
  const float* qw = (const float*)d_in[13];
  const float* kvw = (const float*)d_in[14];
  const float* Wo = (const float*)d_in[15];
  const float* nl = (const float*)d_in[16];
  const float* gl = (const float*)d_in[17];
  const int* am = (const int*)d_in[18];
  float* out = (float*)d_out;
  char* ws = (char*)d_ws;

  // ws layout (bytes); Obuf at 0
  const size_t o_hB = 0;             // bf16 [8192][2048]  33554432  (Obuf)
  const size_t o_Qf = 67108864;      // bf16 [B][H][T][D]  33554432
  const size_t o_A1 = 100663296;     // f32  [8192][256]    8388608
  const size_t o_Qn = 109051904;     // bf16 [8192][128]    2097152
  const size_t o_Kvn = 111149056;    // bf16 [8192][64]     1048576
  const size_t o_kvr = 112197632;    // bf16 [8192][256]    4194304
  const size_t o_Kf = 116391936;     // bf16 [8192][128]    2097152
  const size_t o_Vt = 118489088;     // bf16 [B*128][1024]  2097152
  const size_t o_W1t = 120586240;    // bf16 [256][2048]    1048576
  const size_t o_Wqbt = 121634816;   // bf16 [2048][128]     524288
  const size_t o_Wkbt = 122159104;   // bf16 [256][64]        32768
  const size_t o_Wot = 122191872;    // bf16 [2048][2048]   8388608
  const size_t o_cos = 130580480;    // f32  [65536]         262144
  const size_t o_sin = 130842624;    // f32  [65536]         262144

  unsigned short* Obuf = (unsigned short*)(ws + o_hB);
  unsigned short* Qf = (unsigned short*)(ws + o_Qf);
  float* A1 = (float*)(ws + o_A1);
  unsigned short* Qn = (unsigned short*)(ws + o_Qn);
  unsigned short* Kvn = (unsigned short*)(ws + o_Kvn);
  unsigned short* kvr = (unsigned short*)(ws + o_kvr);
  unsigned short* Kf = (unsigned short*)(ws + o_Kf);
  unsigned short* Vt = (unsigned short*)(ws + o_Vt);
  unsigned short* W1t = (unsigned short*)(ws + o_W1t);
  unsigned short* Wqbt = (unsigned short*)(ws + o_Wqbt);
  unsigned short* Wkbt = (unsigned short*)(ws + o_Wkbt);
  unsigned short* Wot = (unsigned short*)(ws + o_Wot);
  float* cosb = (float*)(ws + o_cos);
  float* sinb = (float*)(ws + o_sin);

  (void)in_sizes; (void)n_in; (void)out_size; (void)ws_size;

  // prep
  k_blend<<<256, 256, 0, stream>>>(cg, sg, cl, sl, gl, cosb, sinb);
  k_zero<<<512, 256, 0, stream>>>(W1t + (size_t)192 * 2048, 64 * 2048);
  k_transpose<<<dim3(4, 64), 256, 0, stream>>>(Wq_a, W1t, 2048, 128);
  k_transpose<<<dim3(2, 64), 256, 0, stream>>>(Wkv_a, W1t + (size_t)128 * 2048, 2048, 64);
  k_transpose<<<dim3(64, 4), 256, 0, stream>>>(Wq_b, Wqbt, 128, 2048);
  k_transpose<<<dim3(8, 2), 256, 0, stream>>>(Wkv_b, Wkbt, 64, 256);
  k_transpose<<<dim3(64, 64), 256, 0, stream>>>(Wo, Wot, 2048, 2048);

  // GEMM1 (fused f32->bf16 A): [8192,2048]@[2048,256] -> fp32  (grid 256)
  k_gemm1<<<256, 256, 0, stream>>>(h, W1t, A1);
  // split rmsnorm
  k_norm<<<2048, 256, 0, stream>>>(A1, bq_a, bkv_a, qw, kvw, Qn, Kvn);
  // GEMM2a + fused RoPE-Q: [8192,128]@[128,2048] -> Qf  (grid 1024 = 64x16)
  k_gemm2q<<<1024, 256, 0, stream>>>(Qn, Wqbt, bq_b, cosb, sinb, nl, Qf);
  // GEMM2b: [8192,64]@[64,256] -> bf16      (grid 128 = 2x64)
  k_gemm<1><<<128, 256, 0, stream>>>(Kvn, Wkbt, kvr, ROWSc, 256, 64, 2);
  // rope + mix for K/V
  k_rope_kv<<<2048, 256, 0, stream>>>(kvr, bkv_b, cosb, sinb, nl, Kf, Vt);
  // attention: 512 blocks ((h*4+spidx)*8+b) x 512 threads, 2 blocks/CU
  k_attn<<<512, 512, 0, stream>>>(Qf, Kf, Vt, am, Obuf);
  // GEMM3: [8192,2048]@[2048,2048] -> fp32 out  (grid 1024 = 16x64)
  k_gemm<0><<<1024, 256, 0, stream>>>(Obuf, Wot, out, ROWSc, HIDc, 2048, 16);
}

// Round 10
// 300.912 us; speedup vs baseline: 1.7421x; 1.7421x over previous
//
#include <hip/hip_runtime.h>
#include <hip/hip_bf16.h>

typedef __attribute__((ext_vector_type(8))) short bf16x8;
typedef __attribute__((ext_vector_type(4))) float f32x4;
typedef __attribute__((ext_vector_type(4))) unsigned short us4;

#define DEV __device__ __forceinline__

constexpr int Bc = 8, Tc = 1024, HIDc = 2048, Hc = 16, Dc = 128;
constexpr int ROWSc = Bc * Tc;  // 8192

DEV unsigned short f2bfb(float x) {
  union { float f; unsigned u; } v; v.f = x;
  unsigned r = v.u + 0x7fffu + ((v.u >> 16) & 1u);  // round-to-nearest-even
  return (unsigned short)(r >> 16);
}
DEV unsigned short f2bfb_fast(float x) {  // round-half-up (2 VALU ops)
  union { float f; unsigned u; } v; v.f = x;
  return (unsigned short)((v.u + 0x8000u) >> 16);
}
DEV float bfb2f(unsigned short b) {
  union { unsigned u; float f; } v; v.u = ((unsigned)b) << 16; return v.f;
}
DEV float fexp2(float x) { return __builtin_amdgcn_exp2f(x); }  // native v_exp_f32

// async global->LDS, 16B per lane; LDS dest = wave-uniform base + lane*16
DEV void gload16(const void* g, void* l) {
  __builtin_amdgcn_global_load_lds(
      (const __attribute__((address_space(1))) unsigned int*)g,
      (__attribute__((address_space(3))) unsigned int*)l, 16, 0, 0);
}

// ---------------- elementwise prep ----------------

__global__ void k_blend(const float* __restrict__ cg, const float* __restrict__ sg,
                        const float* __restrict__ cl, const float* __restrict__ sl,
                        const float* __restrict__ gl,
                        float* __restrict__ cosb, float* __restrict__ sinb) {
  int u = blockIdx.x * 256 + threadIdx.x;
  if (u >= Tc * 64) return;
  float a = 1.0f / (1.0f + __expf(-gl[0]));
  cosb[u] = cg[u] * a + cl[u] * (1.0f - a);
  sinb[u] = sg[u] * a + sl[u] * (1.0f - a);
}

__global__ void k_zero(unsigned short* __restrict__ p, int n) {
  int i = blockIdx.x * 256 + threadIdx.x;
  if (i < n) p[i] = 0;
}

// transpose fp32 [R][C] -> bf16 [C][R]; R,C multiples of 32
__global__ __launch_bounds__(256) void k_transpose(const float* __restrict__ in,
                                                   unsigned short* __restrict__ out,
                                                   int R, int C) {
  __shared__ float tile[32][33];
  int tx = threadIdx.x & 31, ty = threadIdx.x >> 5;
  int r0 = blockIdx.y * 32, c0 = blockIdx.x * 32;
#pragma unroll
  for (int i = 0; i < 4; i++)
    tile[ty + i * 8][tx] = in[(size_t)(r0 + ty + i * 8) * C + c0 + tx];
  __syncthreads();
#pragma unroll
  for (int i = 0; i < 4; i++) {
    int rr = ty + i * 8;
    out[(size_t)(c0 + rr) * R + r0 + tx] = f2bfb(tile[tx][rr]);
  }
}

// ---------------- GEMM1: A1[8192,256] = h_fp32 @ W1t^T, fused f32->bf16 ----------------

__global__ __launch_bounds__(256) void k_gemm1(const float* __restrict__ A,
                                               const unsigned short* __restrict__ Bt,
                                               float* __restrict__ C) {
  constexpr int K = 2048, N = 256;
  __shared__ __align__(16) unsigned short As[64 * 32];
  __shared__ __align__(16) unsigned short Bs[128 * 32];
  int lin = blockIdx.x;
  int wg = (lin & 7) * 32 + (lin >> 3);
  int m0 = (wg >> 1) * 64, n0 = (wg & 1) * 128;
  int tid = threadIdx.x, lane = tid & 63, wc = tid >> 6;
  int ar = tid >> 2, akc = (tid & 3) * 8;
  const float* Ag = A + (size_t)(m0 + ar) * K + akc;
  const unsigned short* Bg0 = Bt + (size_t)(n0 + ar) * K + akc;
  const unsigned short* Bg1 = Bt + (size_t)(n0 + 64 + ar) * K + akc;
  unsigned short* Bsl0 = &Bs[tid * 8];
  unsigned short* Bsl1 = &Bs[2048 + tid * 8];
  f32x4 acc[4][2];
  f32x4 zz = {0.f, 0.f, 0.f, 0.f};
#pragma unroll
  for (int m = 0; m < 4; m++)
#pragma unroll
    for (int n = 0; n < 2; n++) acc[m][n] = zz;
  int fr = lane & 15, fk = (lane >> 4) * 8;
  for (int kt = 0; kt < K; kt += 32) {
    float4 a0 = *(const float4*)(Ag + kt);
    float4 a1 = *(const float4*)(Ag + kt + 4);
    __syncthreads();  // previous iter's frag reads done
    gload16(Bg0 + kt, Bsl0);
    gload16(Bg1 + kt, Bsl1);
    us4 c0 = { f2bfb(a0.x), f2bfb(a0.y), f2bfb(a0.z), f2bfb(a0.w) };
    us4 c1 = { f2bfb(a1.x), f2bfb(a1.y), f2bfb(a1.z), f2bfb(a1.w) };
    *(us4*)&As[ar * 32 + akc] = c0;
    *(us4*)&As[ar * 32 + akc + 4] = c1;
    __syncthreads();  // staged (drains vm+lgkm)
    bf16x8 af[4], bfv[2];
#pragma unroll
    for (int i = 0; i < 4; i++)
      af[i] = *(const bf16x8*)&As[(i * 16 + fr) * 32 + fk];
#pragma unroll
    for (int i = 0; i < 2; i++)
      bfv[i] = *(const bf16x8*)&Bs[(wc * 32 + i * 16 + fr) * 32 + fk];
    __builtin_amdgcn_s_setprio(1);
#pragma unroll
    for (int m = 0; m < 4; m++)
#pragma unroll
      for (int n = 0; n < 2; n++)
        acc[m][n] = __builtin_amdgcn_mfma_f32_16x16x32_bf16(af[m], bfv[n], acc[m][n], 0, 0, 0);
    __builtin_amdgcn_s_setprio(0);
  }
  int gg = lane >> 4;
#pragma unroll
  for (int m = 0; m < 4; m++)
#pragma unroll
    for (int n = 0; n < 2; n++)
#pragma unroll
      for (int r = 0; r < 4; r++) {
        size_t row = (size_t)m0 + m * 16 + gg * 4 + r;
        size_t col = (size_t)n0 + wc * 32 + n * 16 + fr;
        C[row * N + col] = acc[m][n][r];
      }
}

// ---------------- MFMA GEMM (m97 structure): C = A @ Bt^T ----------------
// 128x128 tile, BK=32, 4 waves, global_load_lds width-16 staging.
// 1D grid with XCD-contiguous swizzle (grid%8==0).

template <int OUTB>
__global__ __launch_bounds__(256) void k_gemm(const unsigned short* __restrict__ A,
                                              const unsigned short* __restrict__ Bt,
                                              void* __restrict__ outp,
                                              int M, int N, int K, int nx) {
  __shared__ __align__(16) unsigned short As[4096];  // [128][32]
  __shared__ __align__(16) unsigned short Bs[4096];
  int lin = blockIdx.x;
  int qq = gridDim.x >> 3;
  int wg = (lin & 7) * qq + (lin >> 3);
  int m0 = (wg / nx) * 128, n0 = (wg % nx) * 128;
  int tid = threadIdx.x;
  int lane = tid & 63;
  int wave = tid >> 6;
  int wr = wave >> 1, wc = wave & 1;
  int srow = tid >> 2;
  int skc = (tid & 3) * 8;
  const unsigned short* Ag0 = A + (size_t)(m0 + srow) * K + skc;
  const unsigned short* Ag1 = A + (size_t)(m0 + 64 + srow) * K + skc;
  const unsigned short* Bg0 = Bt + (size_t)(n0 + srow) * K + skc;
  const unsigned short* Bg1 = Bt + (size_t)(n0 + 64 + srow) * K + skc;
  unsigned short* Asl0 = &As[tid * 8];
  unsigned short* Asl1 = &As[2048 + tid * 8];
  unsigned short* Bsl0 = &Bs[tid * 8];
  unsigned short* Bsl1 = &Bs[2048 + tid * 8];
  f32x4 acc[4][4];
  f32x4 zz = {0.f, 0.f, 0.f, 0.f};
#pragma unroll
  for (int m = 0; m < 4; m++)
#pragma unroll
    for (int n = 0; n < 4; n++) acc[m][n] = zz;
  int fr = lane & 15, fk = (lane >> 4) * 8;
  for (int kt = 0; kt < K; kt += 32) {
    __syncthreads();  // previous iter's frag reads done
    gload16(Ag0 + kt, Asl0);
    gload16(Ag1 + kt, Asl1);
    gload16(Bg0 + kt, Bsl0);
    gload16(Bg1 + kt, Bsl1);
    __syncthreads();  // compiler drains vmcnt before barrier
    bf16x8 af[4], bfv[4];
#pragma unroll
    for (int i = 0; i < 4; i++)
      af[i] = *(const bf16x8*)&As[(wr * 64 + i * 16 + fr) * 32 + fk];
#pragma unroll
    for (int i = 0; i < 4; i++)
      bfv[i] = *(const bf16x8*)&Bs[(wc * 64 + i * 16 + fr) * 32 + fk];
    __builtin_amdgcn_s_setprio(1);
#pragma unroll
    for (int m = 0; m < 4; m++)
#pragma unroll
      for (int n = 0; n < 4; n++)
        acc[m][n] = __builtin_amdgcn_mfma_f32_16x16x32_bf16(af[m], bfv[n], acc[m][n], 0, 0, 0);
    __builtin_amdgcn_s_setprio(0);
  }
  int gg = lane >> 4;
#pragma unroll
  for (int m = 0; m < 4; m++)
#pragma unroll
    for (int n = 0; n < 4; n++)
#pragma unroll
      for (int r = 0; r < 4; r++) {
        size_t row = (size_t)m0 + wr * 64 + m * 16 + gg * 4 + r;
        size_t col = (size_t)n0 + wc * 64 + n * 16 + fr;
        if (OUTB)
          ((unsigned short*)outp)[row * N + col] = f2bfb(acc[m][n][r]);
        else
          ((float*)outp)[row * N + col] = acc[m][n][r];
      }
}

// ---------------- GEMM2a + fused RoPE-Q epilogue ----------------
// qfinal = rope_mix(Qn @ Wqbt^T + bqb) * SCLQ, written directly to Qf.

__global__ __launch_bounds__(256) void k_gemm2q(const unsigned short* __restrict__ A,
                                                const unsigned short* __restrict__ Bt,
                                                const float* __restrict__ bqb,
                                                const float* __restrict__ cosb,
                                                const float* __restrict__ sinb,
                                                const float* __restrict__ nl,
                                                unsigned short* __restrict__ Qf) {
  constexpr int K = 128, N = 2048;
  __shared__ __align__(16) unsigned short As[4096];
  __shared__ __align__(16) unsigned short Bs[4096];
  __shared__ __align__(16) unsigned short Qt[128 * 128];  // 32 KB
  int lin = blockIdx.x;
  int wg = (lin & 7) * 128 + (lin >> 3);
  int m0 = (wg >> 4) * 128, n0 = (wg & 15) * 128;
  int h = n0 >> 7;
  int b = m0 >> 10, t0 = m0 & 1023;
  int tid = threadIdx.x;
  int lane = tid & 63;
  int wave = tid >> 6;
  int wr = wave >> 1, wc = wave & 1;
  int srow = tid >> 2;
  int skc = (tid & 3) * 8;
  const unsigned short* Ag0 = A + (size_t)(m0 + srow) * K + skc;
  const unsigned short* Ag1 = A + (size_t)(m0 + 64 + srow) * K + skc;
  const unsigned short* Bg0 = Bt + (size_t)(n0 + srow) * K + skc;
  const unsigned short* Bg1 = Bt + (size_t)(n0 + 64 + srow) * K + skc;
  unsigned short* Asl0 = &As[tid * 8];
  unsigned short* Asl1 = &As[2048 + tid * 8];
  unsigned short* Bsl0 = &Bs[tid * 8];
  unsigned short* Bsl1 = &Bs[2048 + tid * 8];
  f32x4 acc[4][4];
  f32x4 zz = {0.f, 0.f, 0.f, 0.f};
#pragma unroll
  for (int m = 0; m < 4; m++)
#pragma unroll
    for (int n = 0; n < 4; n++) acc[m][n] = zz;
  int fr = lane & 15, fk = (lane >> 4) * 8;
  for (int kt = 0; kt < K; kt += 32) {
    __syncthreads();
    gload16(Ag0 + kt, Asl0);
    gload16(Ag1 + kt, Asl1);
    gload16(Bg0 + kt, Bsl0);
    gload16(Bg1 + kt, Bsl1);
    __syncthreads();
    bf16x8 af[4], bfv[4];
#pragma unroll
    for (int i = 0; i < 4; i++)
      af[i] = *(const bf16x8*)&As[(wr * 64 + i * 16 + fr) * 32 + fk];
#pragma unroll
    for (int i = 0; i < 4; i++)
      bfv[i] = *(const bf16x8*)&Bs[(wc * 64 + i * 16 + fr) * 32 + fk];
    __builtin_amdgcn_s_setprio(1);
#pragma unroll
    for (int m = 0; m < 4; m++)
#pragma unroll
      for (int n = 0; n < 4; n++)
        acc[m][n] = __builtin_amdgcn_mfma_f32_16x16x32_bf16(af[m], bfv[n], acc[m][n], 0, 0, 0);
    __builtin_amdgcn_s_setprio(0);
  }
  // stage biased bf16 tile into LDS (chunk-swizzled rows)
  int gg = lane >> 4;
#pragma unroll
  for (int n = 0; n < 4; n++) {
    int col = wc * 64 + n * 16 + fr;
    float bias = bqb[h * 128 + col];
    int ch = col >> 3, wi = col & 7;
#pragma unroll
    for (int m = 0; m < 4; m++)
#pragma unroll
      for (int r = 0; r < 4; r++) {
        int lrow = wr * 64 + m * 16 + gg * 4 + r;
        Qt[lrow * 128 + ((ch ^ (lrow & 7)) << 3) + wi] = f2bfb(acc[m][n][r] + bias);
      }
  }
  __syncthreads();
  // rope + nope mix + SCLQ, vectorized pairs (d, d+64)
  const float SCLQ = 0.08838834764831845f * 1.4426950408889634f;
  float na = 1.0f / (1.0f + __expf(-nl[0]));
  float nb = 1.0f - na;
#pragma unroll
  for (int it = 0; it < 4; it++) {
    int task = it * 256 + tid;
    int lrow = task >> 3, cp = task & 7;
    int t = t0 + lrow;
    bf16x8 v1 = *(const bf16x8*)&Qt[lrow * 128 + ((cp ^ (lrow & 7)) << 3)];
    bf16x8 v2 = *(const bf16x8*)&Qt[lrow * 128 + (((cp + 8) ^ (lrow & 7)) << 3)];
    float4 cA = *(const float4*)(cosb + t * 64 + cp * 8);
    float4 cB = *(const float4*)(cosb + t * 64 + cp * 8 + 4);
    float4 sA = *(const float4*)(sinb + t * 64 + cp * 8);
    float4 sB = *(const float4*)(sinb + t * 64 + cp * 8 + 4);
    float cv[8] = {cA.x, cA.y, cA.z, cA.w, cB.x, cB.y, cB.z, cB.w};
    float sv[8] = {sA.x, sA.y, sA.z, sA.w, sB.x, sB.y, sB.z, sB.w};
    float f1[8], f2[8];
#pragma unroll
    for (int j = 0; j < 8; j++) {
      float q1 = bfb2f((unsigned short)v1[j]);
      float q2 = bfb2f((unsigned short)v2[j]);
      float p1 = q1 * cv[j] - q2 * sv[j];
      float p2 = q2 * cv[j] + q1 * sv[j];
      f1[j] = (na * q1 + nb * p1) * SCLQ;
      f2[j] = (na * q2 + nb * p2) * SCLQ;
    }
    unsigned short* ob = Qf + ((size_t)(b * Hc + h) * Tc + t) * Dc + cp * 8;
    us4 o0 = {f2bfb(f1[0]), f2bfb(f1[1]), f2bfb(f1[2]), f2bfb(f1[3])};
    us4 o1 = {f2bfb(f1[4]), f2bfb(f1[5]), f2bfb(f1[6]), f2bfb(f1[7])};
    us4 o2 = {f2bfb(f2[0]), f2bfb(f2[1]), f2bfb(f2[2]), f2bfb(f2[3])};
    us4 o3 = {f2bfb(f2[4]), f2bfb(f2[5]), f2bfb(f2[6]), f2bfb(f2[7])};
    *(us4*)(ob) = o0;
    *(us4*)(ob + 4) = o1;
    *(us4*)(ob + 64) = o2;
    *(us4*)(ob + 68) = o3;
  }
}

// ---------------- split RMSNorm (q over 128, kv over 64) ----------------

__global__ __launch_bounds__(256) void k_norm(const float* __restrict__ A1,
                                              const float* __restrict__ bqa,
                                              const float* __restrict__ bkva,
                                              const float* __restrict__ qw,
                                              const float* __restrict__ kvw,
                                              unsigned short* __restrict__ Qn,
                                              unsigned short* __restrict__ Kvn) {
  int wave = threadIdx.x >> 6, lane = threadIdx.x & 63;
  int row = blockIdx.x * 4 + wave;
  const float* a = A1 + (size_t)row * 256;
  float x0 = a[lane] + bqa[lane];
  float x1 = a[64 + lane] + bqa[64 + lane];
  float ss = x0 * x0 + x1 * x1;
#pragma unroll
  for (int off = 1; off < 64; off <<= 1) ss += __shfl_xor(ss, off);
  float sc = rsqrtf(ss * (1.0f / 128.0f) + 1e-6f);
  Qn[(size_t)row * 128 + lane] = f2bfb(x0 * sc * qw[lane]);
  Qn[(size_t)row * 128 + 64 + lane] = f2bfb(x1 * sc * qw[64 + lane]);
  float y = a[128 + lane] + bkva[lane];
  float s2 = y * y;
#pragma unroll
  for (int off = 1; off < 64; off <<= 1) s2 += __shfl_xor(s2, off);
  float sc2 = rsqrtf(s2 * (1.0f / 64.0f) + 1e-6f);
  Kvn[(size_t)row * 64 + lane] = f2bfb(y * sc2 * kvw[lane]);
}

// ---------------- RoPE + nope mix for K/V ----------------

__global__ __launch_bounds__(256) void k_rope_kv(const unsigned short* __restrict__ kvr,
                                                 const float* __restrict__ bkvb,
                                                 const float* __restrict__ cosb,
                                                 const float* __restrict__ sinb,
                                                 const float* __restrict__ nl,
                                                 unsigned short* __restrict__ Kf,
                                                 unsigned short* __restrict__ Vt) {
  int u = blockIdx.x * 256 + threadIdx.x;  // < 8192*64
  int row = u >> 6, d = u & 63;
  int t = row & (Tc - 1), b = row >> 10;
  float na = 1.0f / (1.0f + __expf(-nl[0]));
  const unsigned short* kp = kvr + (size_t)row * 256;
  float k1 = bfb2f(kp[d]) + bkvb[d];
  float k2 = bfb2f(kp[64 + d]) + bkvb[64 + d];
  float v1 = bfb2f(kp[128 + d]) + bkvb[128 + d];
  float v2 = bfb2f(kp[192 + d]) + bkvb[192 + d];
  float cv = cosb[t * 64 + d], sv = sinb[t * 64 + d];
  float p1 = k1 * cv - k2 * sv;
  float p2 = k2 * cv + k1 * sv;
  float f1 = na * k1 + (1.0f - na) * p1;
  float f2 = na * k2 + (1.0f - na) * p2;
  unsigned short* kb = Kf + (size_t)row * Dc;
  kb[d] = f2bfb(f1);
  kb[64 + d] = f2bfb(f2);
  Vt[((size_t)b * Dc + d) * Tc + t] = f2bfb(v1);
  Vt[((size_t)b * Dc + 64 + d) * Tc + t] = f2bfb(v2);
}

// ---------------- flash attention (causal, GQA single KV head) ----------------
// R6/R8-proven geometry: 256 blocks x 512 thr, 8 waves x 32 q-rows = 256-row
// supertile, pairs {0,3}/{1,2} (20 KV-tiles, balanced), bid&7=b XCD affinity.
// Double-buffered KV LDS (1 barrier/tile). __launch_bounds__(512,1): VGPR 128
// + AGPR accum, NO SPILL (R9 lesson: (512,4) forces 128 total regs -> spill).

__global__ __launch_bounds__(512, 1) void k_attn(const unsigned short* __restrict__ Qf,
                                                 const unsigned short* __restrict__ Kf,
                                                 const unsigned short* __restrict__ Vt,
                                                 const int* __restrict__ amask,
                                                 unsigned short* __restrict__ O) {
  __shared__ __align__(16) unsigned short Ks[2][64 * 128];   // [s][d] swizzled
  __shared__ __align__(16) unsigned short Vs[2][128 * 64];   // [d][s] swizzled
  __shared__ __align__(16) unsigned short Plds[8][32 * 64];  // per-wave P
  __shared__ int s_anyzero;

  int bid = blockIdx.x;
  int b = bid & 7;
  int pr = (bid >> 3) & 1;
  int h = bid >> 4;
  int tid = threadIdx.x;
  int wave = tid >> 6, lane = tid & 63;
  int g = lane >> 4, c = lane & 15;

  const unsigned short* Kp = Kf + (size_t)b * Tc * Dc;
  const unsigned short* Vp = Vt + (size_t)b * Dc * Tc;
  const int* mp = amask + b * Tc;
  unsigned short* Pw = &Plds[wave][0];
  f32x4 zz = {0.f, 0.f, 0.f, 0.f};

  // block-level pad-mask prescan (mask is usually all-valid)
  if (tid == 0) s_anyzero = 0;
  __syncthreads();
  if (mp[tid] == 0 || mp[tid + 512] == 0) s_anyzero = 1;
  __syncthreads();
  bool anyz = (s_anyzero != 0);

  // staging geometry: 512 thr; K 64x128 (2 chunks/thr), V 128x64 (2 chunks/thr)
  int kr_ = tid >> 3, kc_ = tid & 7;
  int vr_ = tid >> 2, vc_ = tid & 3;
  int kidx0 = kr_ * 128 + ((kc_ ^ (kr_ & 7)) << 3);
  int kidx1 = kr_ * 128 + (((kc_ + 8) ^ (kr_ & 7)) << 3);
  int vidx0 = vr_ * 64 + ((vc_ ^ (vr_ & 7)) << 3);
  int vidx1 = vr_ * 64 + (((vc_ + 4) ^ (vr_ & 7)) << 3);

  for (int pass = 0; pass < 2; pass++) {
    int sp = (pass == 0) ? pr : 3 - pr;   // supertile: {0,3} or {1,2}
    int qw0 = sp * 256 + wave * 32;
    int nt = (sp + 1) * 4;
    const unsigned short* Qp = Qf + ((size_t)(b * Hc + h) * Tc + qw0) * Dc;
    bf16x8 qfr[2][4];
#pragma unroll
    for (int m = 0; m < 2; m++)
#pragma unroll
      for (int ks = 0; ks < 4; ks++)
        qfr[m][ks] = *(const bf16x8*)(Qp + (size_t)(m * 16 + c) * Dc + ks * 32 + g * 8);

    f32x4 Oacc[2][8];
#pragma unroll
    for (int m = 0; m < 2; m++)
#pragma unroll
      for (int i = 0; i < 8; i++) Oacc[m][i] = zz;
    float m_r[2][4], l_r[2][4];
#pragma unroll
    for (int m = 0; m < 2; m++)
#pragma unroll
      for (int r = 0; r < 4; r++) { m_r[m][r] = -1e30f; l_r[m][r] = 0.f; }

    // prologue: stage tile 0 into buf 0
    bf16x8 krg[2], vrg[2];
    krg[0] = *(const bf16x8*)(Kp + (size_t)kr_ * Dc + kc_ * 8);
    krg[1] = *(const bf16x8*)(Kp + (size_t)kr_ * Dc + kc_ * 8 + 64);
    vrg[0] = *(const bf16x8*)(Vp + (size_t)vr_ * Tc + vc_ * 8);
    vrg[1] = *(const bf16x8*)(Vp + (size_t)vr_ * Tc + vc_ * 8 + 32);
    __syncthreads();  // pass 1: all waves done reading prev pass buffers
    *(bf16x8*)&Ks[0][kidx0] = krg[0];
    *(bf16x8*)&Ks[0][kidx1] = krg[1];
    *(bf16x8*)&Vs[0][vidx0] = vrg[0];
    *(bf16x8*)&Vs[0][vidx1] = vrg[1];
    __syncthreads();  // buf0 staged

    for (int st = 0; st < nt; st++) {
      int cur = st & 1;
      int s0 = st << 6;
      if (st + 1 < nt) {  // issue next-tile loads; latency hides under compute
        int s1 = s0 + 64;
        krg[0] = *(const bf16x8*)(Kp + (size_t)(s1 + kr_) * Dc + kc_ * 8);
        krg[1] = *(const bf16x8*)(Kp + (size_t)(s1 + kr_) * Dc + kc_ * 8 + 64);
        vrg[0] = *(const bf16x8*)(Vp + (size_t)vr_ * Tc + s1 + vc_ * 8);
        vrg[1] = *(const bf16x8*)(Vp + (size_t)vr_ * Tc + s1 + vc_ * 8 + 32);
      }

      if (s0 <= qw0 + 31) {  // wave has unmasked work in this tile
        const unsigned short* Kc = &Ks[cur][0];
        const unsigned short* Vc = &Vs[cur][0];

        // ---- QK^T (exp2 domain, scale pre-folded into Q)
        f32x4 S[2][4];
#pragma unroll
        for (int m = 0; m < 2; m++)
#pragma unroll
          for (int j = 0; j < 4; j++) S[m][j] = zz;
        __builtin_amdgcn_s_setprio(1);
#pragma unroll
        for (int ks = 0; ks < 4; ks++)
#pragma unroll
          for (int j = 0; j < 4; j++) {
            bf16x8 kfr = *(const bf16x8*)&Kc[(j * 16 + c) * 128 + (((ks * 4 + g) ^ (c & 7)) << 3)];
            S[0][j] = __builtin_amdgcn_mfma_f32_16x16x32_bf16(qfr[0][ks], kfr, S[0][j], 0, 0, 0);
            S[1][j] = __builtin_amdgcn_mfma_f32_16x16x32_bf16(qfr[1][ks], kfr, S[1][j], 0, 0, 0);
          }
        __builtin_amdgcn_s_setprio(0);

        // ---- pad mask (only when mask has zeros — prescanned)
        if (anyz) {
#pragma unroll
          for (int j = 0; j < 4; j++) {
            float madd = (mp[s0 + j * 16 + c] == 0) ? -2e9f : 0.0f;
#pragma unroll
            for (int m = 0; m < 2; m++)
#pragma unroll
              for (int r = 0; r < 4; r++) S[m][j][r] += madd;
          }
        }
        // ---- causal edge (tiles overlapping this wave's diagonal)
        if (s0 + 63 > qw0) {
#pragma unroll
          for (int j = 0; j < 4; j++) {
            int s = s0 + j * 16 + c;
#pragma unroll
            for (int m = 0; m < 2; m++)
#pragma unroll
              for (int r = 0; r < 4; r++)
                if (s > qw0 + m * 16 + g * 4 + r) S[m][j][r] = -1e30f;
          }
        }

        // ---- row max, defer-max update (T13)
        float vmax[2][4];
#pragma unroll
        for (int m = 0; m < 2; m++)
#pragma unroll
          for (int r = 0; r < 4; r++) {
            float v = fmaxf(fmaxf(S[m][0][r], S[m][1][r]), fmaxf(S[m][2][r], S[m][3][r]));
            v = fmaxf(v, __shfl_xor(v, 1));
            v = fmaxf(v, __shfl_xor(v, 2));
            v = fmaxf(v, __shfl_xor(v, 4));
            v = fmaxf(v, __shfl_xor(v, 8));
            vmax[m][r] = v;
          }
        bool upd = false;
#pragma unroll
        for (int m = 0; m < 2; m++)
#pragma unroll
          for (int r = 0; r < 4; r++) upd = upd || (vmax[m][r] > m_r[m][r] + 11.0f);
        if (__any(upd)) {
#pragma unroll
          for (int m = 0; m < 2; m++)
#pragma unroll
            for (int r = 0; r < 4; r++) {
              float mn = fmaxf(m_r[m][r], vmax[m][r]);
              float al = fexp2(m_r[m][r] - mn);
              m_r[m][r] = mn;
              l_r[m][r] *= al;
#pragma unroll
              for (int j2 = 0; j2 < 8; j2++) Oacc[m][j2][r] *= al;
            }
        }

        // ---- exp + per-lane l partial + P -> LDS (swizzled)
#pragma unroll
        for (int m = 0; m < 2; m++)
#pragma unroll
          for (int j = 0; j < 4; j++)
#pragma unroll
            for (int r = 0; r < 4; r++) {
              float e = fexp2(S[m][j][r] - m_r[m][r]);
              l_r[m][r] += e;
              int row = m * 16 + g * 4 + r;
              Pw[row * 64 + (((j * 2 + (c >> 3)) ^ (row & 7)) << 3) + (c & 7)] = f2bfb_fast(e);
            }

        // ---- PV: O += P[32q x 64s] @ V^T
        asm volatile("s_waitcnt lgkmcnt(0)" ::: "memory");
        bf16x8 pfr[2][2];
#pragma unroll
        for (int m = 0; m < 2; m++)
#pragma unroll
          for (int sk = 0; sk < 2; sk++) {
            int row = m * 16 + c;
            pfr[m][sk] = *(const bf16x8*)&Pw[row * 64 + (((sk * 4 + g) ^ (row & 7)) << 3)];
          }
        __builtin_amdgcn_s_setprio(1);
#pragma unroll
        for (int sk = 0; sk < 2; sk++)
#pragma unroll
          for (int j2 = 0; j2 < 8; j2++) {
            int row = j2 * 16 + c;
            bf16x8 vfr = *(const bf16x8*)&Vc[row * 64 + (((sk * 4 + g) ^ (row & 7)) << 3)];
            Oacc[0][j2] = __builtin_amdgcn_mfma_f32_16x16x32_bf16(pfr[0][sk], vfr, Oacc[0][j2], 0, 0, 0);
            Oacc[1][j2] = __builtin_amdgcn_mfma_f32_16x16x32_bf16(pfr[1][sk], vfr, Oacc[1][j2], 0, 0, 0);
          }
        __builtin_amdgcn_s_setprio(0);
      }

      if (st + 1 < nt) {  // write next tile into the other buffer
        int nxt = cur ^ 1;
        *(bf16x8*)&Ks[nxt][kidx0] = krg[0];
        *(bf16x8*)&Ks[nxt][kidx1] = krg[1];
        *(bf16x8*)&Vs[nxt][vidx0] = vrg[0];
        *(bf16x8*)&Vs[nxt][vidx1] = vrg[1];
      }
      __syncthreads();  // one barrier per tile: next buf staged, cur reads done
    }

    // ---- epilogue: cross-lane l reduce, normalize, direct stores
#pragma unroll
    for (int m = 0; m < 2; m++)
#pragma unroll
      for (int r = 0; r < 4; r++) {
        float v = l_r[m][r];
        v += __shfl_xor(v, 1);
        v += __shfl_xor(v, 2);
        v += __shfl_xor(v, 4);
        v += __shfl_xor(v, 8);
        float inv = 1.0f / v;
        int qr = qw0 + m * 16 + g * 4 + r;
        unsigned short* ob = O + ((size_t)(b * Tc) + qr) * HIDc + h * Dc;
#pragma unroll
        for (int j2 = 0; j2 < 8; j2++) ob[j2 * 16 + c] = f2bfb(Oacc[m][j2][r] * inv);
      }
  }
}

// ---------------- host launch ----------------

extern "C" void kernel_launch(void* const* d_in, const int* in_sizes, int n_in,
                              void* d_out, int out_size, void* d_ws, size_t ws_size,
                              hipStream_t stream) {
  const float* h = (const float*)d_in[0];
  const float* cg = (const float*)d_in[1];
  const float* sg = (const float*)d_in[2];
  const float* cl = (const float*)d_in[3];
  const float* sl = (const float*)d_in[4];
  const float* Wq_a = (const float*)d_in[5];
  const float* bq_a = (const float*)d_in[6];
  const float* Wq_b = (const float*)d_in[7];
  const float* bq_b = (const float*)d_in[8];
  const float* Wkv_a = (const float*)d_in[9];
  const float* bkv_a = (const float*)d_in[10];
  const float* Wkv_b = (const float*)d_in[11];
  const float* bkv_b = (const float*)d_in[12];
  const float* qw = (const float*)d_in[13];
  const float* kvw = (const float*)d_in[14];
  const float* Wo = (const float*)d_in[15];
  const float* nl = (const float*)d_in[16];
  const float* gl = (const float*)d_in[17];
  const int* am = (const int*)d_in[18];
  float* out = (float*)d_out;
  char* ws = (char*)d_ws;

  // ws layout (bytes); Obuf at 0
  const size_t o_hB = 0;             // bf16 [8192][2048]  33554432  (Obuf)
  const size_t o_Qf = 67108864;      // bf16 [B][H][T][D]  33554432
  const size_t o_A1 = 100663296;     // f32  [8192][256]    8388608
  const size_t o_Qn = 109051904;     // bf16 [8192][128]    2097152
  const size_t o_Kvn = 111149056;    // bf16 [8192][64]     1048576
  const size_t o_kvr = 112197632;    // bf16 [8192][256]    4194304
  const size_t o_Kf = 116391936;     // bf16 [8192][128]    2097152
  const size_t o_Vt = 118489088;     // bf16 [B*128][1024]  2097152
  const size_t o_W1t = 120586240;    // bf16 [256][2048]    1048576
  const size_t o_Wqbt = 121634816;   // bf16 [2048][128]     524288
  const size_t o_Wkbt = 122159104;   // bf16 [256][64]        32768
  const size_t o_Wot = 122191872;    // bf16 [2048][2048]   8388608
  const size_t o_cos = 130580480;    // f32  [65536]         262144
  const size_t o_sin = 130842624;    // f32  [65536]         262144

  unsigned short* Obuf = (unsigned short*)(ws + o_hB);
  unsigned short* Qf = (unsigned short*)(ws + o_Qf);
  float* A1 = (float*)(ws + o_A1);
  unsigned short* Qn = (unsigned short*)(ws + o_Qn);
  unsigned short* Kvn = (unsigned short*)(ws + o_Kvn);
  unsigned short* kvr = (unsigned short*)(ws + o_kvr);
  unsigned short* Kf = (unsigned short*)(ws + o_Kf);
  unsigned short* Vt = (unsigned short*)(ws + o_Vt);
  unsigned short* W1t = (unsigned short*)(ws + o_W1t);
  unsigned short* Wqbt = (unsigned short*)(ws + o_Wqbt);
  unsigned short* Wkbt = (unsigned short*)(ws + o_Wkbt);
  unsigned short* Wot = (unsigned short*)(ws + o_Wot);
  float* cosb = (float*)(ws + o_cos);
  float* sinb = (float*)(ws + o_sin);

  (void)in_sizes; (void)n_in; (void)out_size; (void)ws_size;

  // prep
  k_blend<<<256, 256, 0, stream>>>(cg, sg, cl, sl, gl, cosb, sinb);
  k_zero<<<512, 256, 0, stream>>>(W1t + (size_t)192 * 2048, 64 * 2048);
  k_transpose<<<dim3(4, 64), 256, 0, stream>>>(Wq_a, W1t, 2048, 128);
  k_transpose<<<dim3(2, 64), 256, 0, stream>>>(Wkv_a, W1t + (size_t)128 * 2048, 2048, 64);
  k_transpose<<<dim3(64, 4), 256, 0, stream>>>(Wq_b, Wqbt, 128, 2048);
  k_transpose<<<dim3(8, 2), 256, 0, stream>>>(Wkv_b, Wkbt, 64, 256);
  k_transpose<<<dim3(64, 64), 256, 0, stream>>>(Wo, Wot, 2048, 2048);

  // GEMM1 (fused f32->bf16 A): [8192,2048]@[2048,256] -> fp32  (grid 256)
  k_gemm1<<<256, 256, 0, stream>>>(h, W1t, A1);
  // split rmsnorm
  k_norm<<<2048, 256, 0, stream>>>(A1, bq_a, bkv_a, qw, kvw, Qn, Kvn);
  // GEMM2a + fused RoPE-Q: [8192,128]@[128,2048] -> Qf  (grid 1024 = 64x16)
  k_gemm2q<<<1024, 256, 0, stream>>>(Qn, Wqbt, bq_b, cosb, sinb, nl, Qf);
  // GEMM2b: [8192,64]@[64,256] -> bf16      (grid 128 = 2x64)
  k_gemm<1><<<128, 256, 0, stream>>>(Kvn, Wkbt, kvr, ROWSc, 256, 64, 2);
  // rope + mix for K/V
  k_rope_kv<<<2048, 256, 0, stream>>>(kvr, bkv_b, cosb, sinb, nl, Kf, Vt);
  // attention: 256 blocks (h*16 + pair*8 + b) x 512 threads (R6/R8 geometry)
  k_attn<<<256, 512, 0, stream>>>(Qf, Kf, Vt, am, Obuf);
  // GEMM3: [8192,2048]@[2048,2048] -> fp32 out  (grid 1024 = 16x64)
  k_gemm<0><<<1024, 256, 0, stream>>>(Obuf, Wot, out, ROWSc, HIDc, 2048, 16);
}

// Round 11
// 255.068 us; speedup vs baseline: 2.0552x; 1.1797x over previous
//
#include <hip/hip_runtime.h>
#include <hip/hip_bf16.h>

typedef __attribute__((ext_vector_type(8))) short bf16x8;
typedef __attribute__((ext_vector_type(4))) float f32x4;
typedef __attribute__((ext_vector_type(4))) unsigned short us4;

#define DEV __device__ __forceinline__

constexpr int Bc = 8, Tc = 1024, HIDc = 2048, Hc = 16, Dc = 128;
constexpr int ROWSc = Bc * Tc;  // 8192

DEV unsigned short f2bfb(float x) {
  union { float f; unsigned u; } v; v.f = x;
  unsigned r = v.u + 0x7fffu + ((v.u >> 16) & 1u);  // round-to-nearest-even
  return (unsigned short)(r >> 16);
}
DEV float bfb2f(unsigned short b) {
  union { unsigned u; float f; } v; v.u = ((unsigned)b) << 16; return v.f;
}
DEV float fexp2(float x) { return __builtin_amdgcn_exp2f(x); }  // native v_exp_f32
DEV unsigned pkbf(float lo, float hi) {  // 2 bf16 (round-half-up) packed in u32
  union { float f; unsigned u; } a, b; a.f = lo; b.f = hi;
  return ((b.u + 0x8000u) & 0xffff0000u) | ((a.u + 0x8000u) >> 16);
}

// async global->LDS, 16B per lane; LDS dest = wave-uniform base + lane*16
DEV void gload16(const void* g, void* l) {
  __builtin_amdgcn_global_load_lds(
      (const __attribute__((address_space(1))) unsigned int*)g,
      (__attribute__((address_space(3))) unsigned int*)l, 16, 0, 0);
}

// ---------------- elementwise prep ----------------

__global__ void k_blend(const float* __restrict__ cg, const float* __restrict__ sg,
                        const float* __restrict__ cl, const float* __restrict__ sl,
                        const float* __restrict__ gl,
                        float* __restrict__ cosb, float* __restrict__ sinb) {
  int u = blockIdx.x * 256 + threadIdx.x;
  if (u >= Tc * 64) return;
  float a = 1.0f / (1.0f + __expf(-gl[0]));
  cosb[u] = cg[u] * a + cl[u] * (1.0f - a);
  sinb[u] = sg[u] * a + sl[u] * (1.0f - a);
}

__global__ void k_zero(unsigned short* __restrict__ p, int n) {
  int i = blockIdx.x * 256 + threadIdx.x;
  if (i < n) p[i] = 0;
}

// transpose fp32 [R][C] -> bf16 [C][R]; R,C multiples of 32
__global__ __launch_bounds__(256) void k_transpose(const float* __restrict__ in,
                                                   unsigned short* __restrict__ out,
                                                   int R, int C) {
  __shared__ float tile[32][33];
  int tx = threadIdx.x & 31, ty = threadIdx.x >> 5;
  int r0 = blockIdx.y * 32, c0 = blockIdx.x * 32;
#pragma unroll
  for (int i = 0; i < 4; i++)
    tile[ty + i * 8][tx] = in[(size_t)(r0 + ty + i * 8) * C + c0 + tx];
  __syncthreads();
#pragma unroll
  for (int i = 0; i < 4; i++) {
    int rr = ty + i * 8;
    out[(size_t)(c0 + rr) * R + r0 + tx] = f2bfb(tile[tx][rr]);
  }
}

// ---------------- GEMM1: A1[8192,256] = h_fp32 @ W1t^T, fused f32->bf16 ----------------

__global__ __launch_bounds__(256) void k_gemm1(const float* __restrict__ A,
                                               const unsigned short* __restrict__ Bt,
                                               float* __restrict__ C) {
  constexpr int K = 2048, N = 256;
  __shared__ __align__(16) unsigned short As[64 * 32];
  __shared__ __align__(16) unsigned short Bs[128 * 32];
  int lin = blockIdx.x;
  int wg = (lin & 7) * 32 + (lin >> 3);
  int m0 = (wg >> 1) * 64, n0 = (wg & 1) * 128;
  int tid = threadIdx.x, lane = tid & 63, wc = tid >> 6;
  int ar = tid >> 2, akc = (tid & 3) * 8;
  const float* Ag = A + (size_t)(m0 + ar) * K + akc;
  const unsigned short* Bg0 = Bt + (size_t)(n0 + ar) * K + akc;
  const unsigned short* Bg1 = Bt + (size_t)(n0 + 64 + ar) * K + akc;
  unsigned short* Bsl0 = &Bs[tid * 8];
  unsigned short* Bsl1 = &Bs[2048 + tid * 8];
  f32x4 acc[4][2];
  f32x4 zz = {0.f, 0.f, 0.f, 0.f};
#pragma unroll
  for (int m = 0; m < 4; m++)
#pragma unroll
    for (int n = 0; n < 2; n++) acc[m][n] = zz;
  int fr = lane & 15, fk = (lane >> 4) * 8;
  for (int kt = 0; kt < K; kt += 32) {
    float4 a0 = *(const float4*)(Ag + kt);
    float4 a1 = *(const float4*)(Ag + kt + 4);
    __syncthreads();  // previous iter's frag reads done
    gload16(Bg0 + kt, Bsl0);
    gload16(Bg1 + kt, Bsl1);
    us4 c0 = { f2bfb(a0.x), f2bfb(a0.y), f2bfb(a0.z), f2bfb(a0.w) };
    us4 c1 = { f2bfb(a1.x), f2bfb(a1.y), f2bfb(a1.z), f2bfb(a1.w) };
    *(us4*)&As[ar * 32 + akc] = c0;
    *(us4*)&As[ar * 32 + akc + 4] = c1;
    __syncthreads();  // staged (drains vm+lgkm)
    bf16x8 af[4], bfv[2];
#pragma unroll
    for (int i = 0; i < 4; i++)
      af[i] = *(const bf16x8*)&As[(i * 16 + fr) * 32 + fk];
#pragma unroll
    for (int i = 0; i < 2; i++)
      bfv[i] = *(const bf16x8*)&Bs[(wc * 32 + i * 16 + fr) * 32 + fk];
    __builtin_amdgcn_s_setprio(1);
#pragma unroll
    for (int m = 0; m < 4; m++)
#pragma unroll
      for (int n = 0; n < 2; n++)
        acc[m][n] = __builtin_amdgcn_mfma_f32_16x16x32_bf16(af[m], bfv[n], acc[m][n], 0, 0, 0);
    __builtin_amdgcn_s_setprio(0);
  }
  int gg = lane >> 4;
#pragma unroll
  for (int m = 0; m < 4; m++)
#pragma unroll
    for (int n = 0; n < 2; n++)
#pragma unroll
      for (int r = 0; r < 4; r++) {
        size_t row = (size_t)m0 + m * 16 + gg * 4 + r;
        size_t col = (size_t)n0 + wc * 32 + n * 16 + fr;
        C[row * N + col] = acc[m][n][r];
      }
}

// ---------------- MFMA GEMM (m97 structure): C = A @ Bt^T ----------------
// 128x128 tile, BK=32, 4 waves, global_load_lds width-16 staging.
// 1D grid with XCD-contiguous swizzle (grid%8==0).

template <int OUTB>
__global__ __launch_bounds__(256) void k_gemm(const unsigned short* __restrict__ A,
                                              const unsigned short* __restrict__ Bt,
                                              void* __restrict__ outp,
                                              int M, int N, int K, int nx) {
  __shared__ __align__(16) unsigned short As[4096];  // [128][32]
  __shared__ __align__(16) unsigned short Bs[4096];
  int lin = blockIdx.x;
  int qq = gridDim.x >> 3;
  int wg = (lin & 7) * qq + (lin >> 3);
  int m0 = (wg / nx) * 128, n0 = (wg % nx) * 128;
  int tid = threadIdx.x;
  int lane = tid & 63;
  int wave = tid >> 6;
  int wr = wave >> 1, wc = wave & 1;
  int srow = tid >> 2;
  int skc = (tid & 3) * 8;
  const unsigned short* Ag0 = A + (size_t)(m0 + srow) * K + skc;
  const unsigned short* Ag1 = A + (size_t)(m0 + 64 + srow) * K + skc;
  const unsigned short* Bg0 = Bt + (size_t)(n0 + srow) * K + skc;
  const unsigned short* Bg1 = Bt + (size_t)(n0 + 64 + srow) * K + skc;
  unsigned short* Asl0 = &As[tid * 8];
  unsigned short* Asl1 = &As[2048 + tid * 8];
  unsigned short* Bsl0 = &Bs[tid * 8];
  unsigned short* Bsl1 = &Bs[2048 + tid * 8];
  f32x4 acc[4][4];
  f32x4 zz = {0.f, 0.f, 0.f, 0.f};
#pragma unroll
  for (int m = 0; m < 4; m++)
#pragma unroll
    for (int n = 0; n < 4; n++) acc[m][n] = zz;
  int fr = lane & 15, fk = (lane >> 4) * 8;
  for (int kt = 0; kt < K; kt += 32) {
    __syncthreads();  // previous iter's frag reads done
    gload16(Ag0 + kt, Asl0);
    gload16(Ag1 + kt, Asl1);
    gload16(Bg0 + kt, Bsl0);
    gload16(Bg1 + kt, Bsl1);
    __syncthreads();  // compiler drains vmcnt before barrier
    bf16x8 af[4], bfv[4];
#pragma unroll
    for (int i = 0; i < 4; i++)
      af[i] = *(const bf16x8*)&As[(wr * 64 + i * 16 + fr) * 32 + fk];
#pragma unroll
    for (int i = 0; i < 4; i++)
      bfv[i] = *(const bf16x8*)&Bs[(wc * 64 + i * 16 + fr) * 32 + fk];
    __builtin_amdgcn_s_setprio(1);
#pragma unroll
    for (int m = 0; m < 4; m++)
#pragma unroll
      for (int n = 0; n < 4; n++)
        acc[m][n] = __builtin_amdgcn_mfma_f32_16x16x32_bf16(af[m], bfv[n], acc[m][n], 0, 0, 0);
    __builtin_amdgcn_s_setprio(0);
  }
  int gg = lane >> 4;
#pragma unroll
  for (int m = 0; m < 4; m++)
#pragma unroll
    for (int n = 0; n < 4; n++)
#pragma unroll
      for (int r = 0; r < 4; r++) {
        size_t row = (size_t)m0 + wr * 64 + m * 16 + gg * 4 + r;
        size_t col = (size_t)n0 + wc * 64 + n * 16 + fr;
        if (OUTB)
          ((unsigned short*)outp)[row * N + col] = f2bfb(acc[m][n][r]);
        else
          ((float*)outp)[row * N + col] = acc[m][n][r];
      }
}

// ---------------- GEMM2a + fused RoPE-Q epilogue ----------------
// qfinal = rope_mix(Qn @ Wqbt^T + bqb) * SCLQ, written directly to Qf.

__global__ __launch_bounds__(256) void k_gemm2q(const unsigned short* __restrict__ A,
                                                const unsigned short* __restrict__ Bt,
                                                const float* __restrict__ bqb,
                                                const float* __restrict__ cosb,
                                                const float* __restrict__ sinb,
                                                const float* __restrict__ nl,
                                                unsigned short* __restrict__ Qf) {
  constexpr int K = 128, N = 2048;
  __shared__ __align__(16) unsigned short As[4096];
  __shared__ __align__(16) unsigned short Bs[4096];
  __shared__ __align__(16) unsigned short Qt[128 * 128];  // 32 KB
  int lin = blockIdx.x;
  int wg = (lin & 7) * 128 + (lin >> 3);
  int m0 = (wg >> 4) * 128, n0 = (wg & 15) * 128;
  int h = n0 >> 7;
  int b = m0 >> 10, t0 = m0 & 1023;
  int tid = threadIdx.x;
  int lane = tid & 63;
  int wave = tid >> 6;
  int wr = wave >> 1, wc = wave & 1;
  int srow = tid >> 2;
  int skc = (tid & 3) * 8;
  const unsigned short* Ag0 = A + (size_t)(m0 + srow) * K + skc;
  const unsigned short* Ag1 = A + (size_t)(m0 + 64 + srow) * K + skc;
  const unsigned short* Bg0 = Bt + (size_t)(n0 + srow) * K + skc;
  const unsigned short* Bg1 = Bt + (size_t)(n0 + 64 + srow) * K + skc;
  unsigned short* Asl0 = &As[tid * 8];
  unsigned short* Asl1 = &As[2048 + tid * 8];
  unsigned short* Bsl0 = &Bs[tid * 8];
  unsigned short* Bsl1 = &Bs[2048 + tid * 8];
  f32x4 acc[4][4];
  f32x4 zz = {0.f, 0.f, 0.f, 0.f};
#pragma unroll
  for (int m = 0; m < 4; m++)
#pragma unroll
    for (int n = 0; n < 4; n++) acc[m][n] = zz;
  int fr = lane & 15, fk = (lane >> 4) * 8;
  for (int kt = 0; kt < K; kt += 32) {
    __syncthreads();
    gload16(Ag0 + kt, Asl0);
    gload16(Ag1 + kt, Asl1);
    gload16(Bg0 + kt, Bsl0);
    gload16(Bg1 + kt, Bsl1);
    __syncthreads();
    bf16x8 af[4], bfv[4];
#pragma unroll
    for (int i = 0; i < 4; i++)
      af[i] = *(const bf16x8*)&As[(wr * 64 + i * 16 + fr) * 32 + fk];
#pragma unroll
    for (int i = 0; i < 4; i++)
      bfv[i] = *(const bf16x8*)&Bs[(wc * 64 + i * 16 + fr) * 32 + fk];
    __builtin_amdgcn_s_setprio(1);
#pragma unroll
    for (int m = 0; m < 4; m++)
#pragma unroll
      for (int n = 0; n < 4; n++)
        acc[m][n] = __builtin_amdgcn_mfma_f32_16x16x32_bf16(af[m], bfv[n], acc[m][n], 0, 0, 0);
    __builtin_amdgcn_s_setprio(0);
  }
  // stage biased bf16 tile into LDS (chunk-swizzled rows)
  int gg = lane >> 4;
#pragma unroll
  for (int n = 0; n < 4; n++) {
    int col = wc * 64 + n * 16 + fr;
    float bias = bqb[h * 128 + col];
    int ch = col >> 3, wi = col & 7;
#pragma unroll
    for (int m = 0; m < 4; m++)
#pragma unroll
      for (int r = 0; r < 4; r++) {
        int lrow = wr * 64 + m * 16 + gg * 4 + r;
        Qt[lrow * 128 + ((ch ^ (lrow & 7)) << 3) + wi] = f2bfb(acc[m][n][r] + bias);
      }
  }
  __syncthreads();
  // rope + nope mix + SCLQ, vectorized pairs (d, d+64)
  const float SCLQ = 0.08838834764831845f * 1.4426950408889634f;
  float na = 1.0f / (1.0f + __expf(-nl[0]));
  float nb = 1.0f - na;
#pragma unroll
  for (int it = 0; it < 4; it++) {
    int task = it * 256 + tid;
    int lrow = task >> 3, cp = task & 7;
    int t = t0 + lrow;
    bf16x8 v1 = *(const bf16x8*)&Qt[lrow * 128 + ((cp ^ (lrow & 7)) << 3)];
    bf16x8 v2 = *(const bf16x8*)&Qt[lrow * 128 + (((cp + 8) ^ (lrow & 7)) << 3)];
    float4 cA = *(const float4*)(cosb + t * 64 + cp * 8);
    float4 cB = *(const float4*)(cosb + t * 64 + cp * 8 + 4);
    float4 sA = *(const float4*)(sinb + t * 64 + cp * 8);
    float4 sB = *(const float4*)(sinb + t * 64 + cp * 8 + 4);
    float cv[8] = {cA.x, cA.y, cA.z, cA.w, cB.x, cB.y, cB.z, cB.w};
    float sv[8] = {sA.x, sA.y, sA.z, sA.w, sB.x, sB.y, sB.z, sB.w};
    float f1[8], f2[8];
#pragma unroll
    for (int j = 0; j < 8; j++) {
      float q1 = bfb2f((unsigned short)v1[j]);
      float q2 = bfb2f((unsigned short)v2[j]);
      float p1 = q1 * cv[j] - q2 * sv[j];
      float p2 = q2 * cv[j] + q1 * sv[j];
      f1[j] = (na * q1 + nb * p1) * SCLQ;
      f2[j] = (na * q2 + nb * p2) * SCLQ;
    }
    unsigned short* ob = Qf + ((size_t)(b * Hc + h) * Tc + t) * Dc + cp * 8;
    us4 o0 = {f2bfb(f1[0]), f2bfb(f1[1]), f2bfb(f1[2]), f2bfb(f1[3])};
    us4 o1 = {f2bfb(f1[4]), f2bfb(f1[5]), f2bfb(f1[6]), f2bfb(f1[7])};
    us4 o2 = {f2bfb(f2[0]), f2bfb(f2[1]), f2bfb(f2[2]), f2bfb(f2[3])};
    us4 o3 = {f2bfb(f2[4]), f2bfb(f2[5]), f2bfb(f2[6]), f2bfb(f2[7])};
    *(us4*)(ob) = o0;
    *(us4*)(ob + 4) = o1;
    *(us4*)(ob + 64) = o2;
    *(us4*)(ob + 68) = o3;
  }
}

// ---------------- split RMSNorm (q over 128, kv over 64) ----------------

__global__ __launch_bounds__(256) void k_norm(const float* __restrict__ A1,
                                              const float* __restrict__ bqa,
                                              const float* __restrict__ bkva,
                                              const float* __restrict__ qw,
                                              const float* __restrict__ kvw,
                                              unsigned short* __restrict__ Qn,
                                              unsigned short* __restrict__ Kvn) {
  int wave = threadIdx.x >> 6, lane = threadIdx.x & 63;
  int row = blockIdx.x * 4 + wave;
  const float* a = A1 + (size_t)row * 256;
  float x0 = a[lane] + bqa[lane];
  float x1 = a[64 + lane] + bqa[64 + lane];
  float ss = x0 * x0 + x1 * x1;
#pragma unroll
  for (int off = 1; off < 64; off <<= 1) ss += __shfl_xor(ss, off);
  float sc = rsqrtf(ss * (1.0f / 128.0f) + 1e-6f);
  Qn[(size_t)row * 128 + lane] = f2bfb(x0 * sc * qw[lane]);
  Qn[(size_t)row * 128 + 64 + lane] = f2bfb(x1 * sc * qw[64 + lane]);
  float y = a[128 + lane] + bkva[lane];
  float s2 = y * y;
#pragma unroll
  for (int off = 1; off < 64; off <<= 1) s2 += __shfl_xor(s2, off);
  float sc2 = rsqrtf(s2 * (1.0f / 64.0f) + 1e-6f);
  Kvn[(size_t)row * 64 + lane] = f2bfb(y * sc2 * kvw[lane]);
}

// ---------------- RoPE + nope mix for K/V ----------------

__global__ __launch_bounds__(256) void k_rope_kv(const unsigned short* __restrict__ kvr,
                                                 const float* __restrict__ bkvb,
                                                 const float* __restrict__ cosb,
                                                 const float* __restrict__ sinb,
                                                 const float* __restrict__ nl,
                                                 unsigned short* __restrict__ Kf,
                                                 unsigned short* __restrict__ Vt) {
  int u = blockIdx.x * 256 + threadIdx.x;  // < 8192*64
  int row = u >> 6, d = u & 63;
  int t = row & (Tc - 1), b = row >> 10;
  float na = 1.0f / (1.0f + __expf(-nl[0]));
  const unsigned short* kp = kvr + (size_t)row * 256;
  float k1 = bfb2f(kp[d]) + bkvb[d];
  float k2 = bfb2f(kp[64 + d]) + bkvb[64 + d];
  float v1 = bfb2f(kp[128 + d]) + bkvb[128 + d];
  float v2 = bfb2f(kp[192 + d]) + bkvb[192 + d];
  float cv = cosb[t * 64 + d], sv = sinb[t * 64 + d];
  float p1 = k1 * cv - k2 * sv;
  float p2 = k2 * cv + k1 * sv;
  float f1 = na * k1 + (1.0f - na) * p1;
  float f2 = na * k2 + (1.0f - na) * p2;
  unsigned short* kb = Kf + (size_t)row * Dc;
  kb[d] = f2bfb(f1);
  kb[64 + d] = f2bfb(f2);
  Vt[((size_t)b * Dc + d) * Tc + t] = f2bfb(v1);
  Vt[((size_t)b * Dc + 64 + d) * Tc + t] = f2bfb(v2);
}

// ---------------- flash attention (causal, GQA single KV head) ----------------
// R6/R8 geometry: 256 blocks x 512 thr, 8 waves x 32 q-rows, pairs {0,3}/{1,2},
// bid&7=b XCD affinity, dbuf KV LDS. NEW (R11): SWAPPED QK^T — S^T = mfma(K,Q)
// puts each lane's 32 S-values on ONE q-row pair (q=m*16+c, 16 lane-local k's):
// row-max = 15 fmax + 2 shfl (was 32 shfl); P-write = 8 ds_write_b64 (was 32
// b16). Rescale/epilogue broadcast per-q stats via 8 shfl (rare/once).

__global__ __launch_bounds__(512, 1) void k_attn(const unsigned short* __restrict__ Qf,
                                                 const unsigned short* __restrict__ Kf,
                                                 const unsigned short* __restrict__ Vt,
                                                 const int* __restrict__ amask,
                                                 unsigned short* __restrict__ O) {
  __shared__ __align__(16) unsigned short Ks[2][64 * 128];   // [s][d] swizzled
  __shared__ __align__(16) unsigned short Vs[2][128 * 64];   // [d][s] swizzled
  __shared__ __align__(16) unsigned short Plds[8][32 * 64];  // per-wave P [q][k] swz
  __shared__ int s_anyzero;

  int bid = blockIdx.x;
  int b = bid & 7;
  int pr = (bid >> 3) & 1;
  int h = bid >> 4;
  int tid = threadIdx.x;
  int wave = tid >> 6, lane = tid & 63;
  int g = lane >> 4, c = lane & 15;

  const unsigned short* Kp = Kf + (size_t)b * Tc * Dc;
  const unsigned short* Vp = Vt + (size_t)b * Dc * Tc;
  const int* mp = amask + b * Tc;
  char* PwB = (char*)&Plds[wave][0];
  f32x4 zz = {0.f, 0.f, 0.f, 0.f};

  // block-level pad-mask prescan (mask is usually all-valid)
  if (tid == 0) s_anyzero = 0;
  __syncthreads();
  if (mp[tid] == 0 || mp[tid + 512] == 0) s_anyzero = 1;
  __syncthreads();
  bool anyz = (s_anyzero != 0);

  // staging geometry: 512 thr; K 64x128 (2 chunks/thr), V 128x64 (2 chunks/thr)
  int kr_ = tid >> 3, kc_ = tid & 7;
  int vr_ = tid >> 2, vc_ = tid & 3;
  int kidx0 = kr_ * 128 + ((kc_ ^ (kr_ & 7)) << 3);
  int kidx1 = kr_ * 128 + (((kc_ + 8) ^ (kr_ & 7)) << 3);
  int vidx0 = vr_ * 64 + ((vc_ ^ (vr_ & 7)) << 3);
  int vidx1 = vr_ * 64 + (((vc_ + 4) ^ (vr_ & 7)) << 3);

  int c7s = (c & 7) << 4;       // byte swizzle within P row
  int g4 = g * 4;

  for (int pass = 0; pass < 2; pass++) {
    int sp = (pass == 0) ? pr : 3 - pr;   // supertile: {0,3} or {1,2}
    int qw0 = sp * 256 + wave * 32;
    int nt = (sp + 1) * 4;
    const unsigned short* Qp = Qf + ((size_t)(b * Hc + h) * Tc + qw0) * Dc;
    bf16x8 qfr[2][4];
#pragma unroll
    for (int m = 0; m < 2; m++)
#pragma unroll
      for (int ks = 0; ks < 4; ks++)
        qfr[m][ks] = *(const bf16x8*)(Qp + (size_t)(m * 16 + c) * Dc + ks * 32 + g * 8);

    f32x4 Oacc[2][8];
#pragma unroll
    for (int m = 0; m < 2; m++)
#pragma unroll
      for (int i = 0; i < 8; i++) Oacc[m][i] = zz;
    float m_r[2] = {-1e30f, -1e30f};
    float l_r[2] = {0.f, 0.f};

    // prologue: stage tile 0 into buf 0
    bf16x8 krg[2], vrg[2];
    krg[0] = *(const bf16x8*)(Kp + (size_t)kr_ * Dc + kc_ * 8);
    krg[1] = *(const bf16x8*)(Kp + (size_t)kr_ * Dc + kc_ * 8 + 64);
    vrg[0] = *(const bf16x8*)(Vp + (size_t)vr_ * Tc + vc_ * 8);
    vrg[1] = *(const bf16x8*)(Vp + (size_t)vr_ * Tc + vc_ * 8 + 32);
    __syncthreads();  // pass 1: all waves done reading prev pass buffers
    *(bf16x8*)&Ks[0][kidx0] = krg[0];
    *(bf16x8*)&Ks[0][kidx1] = krg[1];
    *(bf16x8*)&Vs[0][vidx0] = vrg[0];
    *(bf16x8*)&Vs[0][vidx1] = vrg[1];
    __syncthreads();  // buf0 staged

    for (int st = 0; st < nt; st++) {
      int cur = st & 1;
      int s0 = st << 6;
      if (st + 1 < nt) {  // issue next-tile loads; latency hides under compute
        int s1 = s0 + 64;
        krg[0] = *(const bf16x8*)(Kp + (size_t)(s1 + kr_) * Dc + kc_ * 8);
        krg[1] = *(const bf16x8*)(Kp + (size_t)(s1 + kr_) * Dc + kc_ * 8 + 64);
        vrg[0] = *(const bf16x8*)(Vp + (size_t)vr_ * Tc + s1 + vc_ * 8);
        vrg[1] = *(const bf16x8*)(Vp + (size_t)vr_ * Tc + s1 + vc_ * 8 + 32);
      }

      if (s0 <= qw0 + 31) {  // wave has unmasked work in this tile
        const unsigned short* Kc = &Ks[cur][0];
        const unsigned short* Vc = &Vs[cur][0];

        // ---- swapped QK^T: S^T[k][q]; lane (g,c) holds
        // S[q = qw0+m*16+c][k = s0 + j*16 + g*4 + r]
        f32x4 S[2][4];
#pragma unroll
        for (int m = 0; m < 2; m++)
#pragma unroll
          for (int j = 0; j < 4; j++) S[m][j] = zz;
        __builtin_amdgcn_s_setprio(1);
#pragma unroll
        for (int ks = 0; ks < 4; ks++)
#pragma unroll
          for (int j = 0; j < 4; j++) {
            bf16x8 kfr = *(const bf16x8*)&Kc[(j * 16 + c) * 128 + (((ks * 4 + g) ^ (c & 7)) << 3)];
            S[0][j] = __builtin_amdgcn_mfma_f32_16x16x32_bf16(kfr, qfr[0][ks], S[0][j], 0, 0, 0);
            S[1][j] = __builtin_amdgcn_mfma_f32_16x16x32_bf16(kfr, qfr[1][ks], S[1][j], 0, 0, 0);
          }
        __builtin_amdgcn_s_setprio(0);

        // ---- pad mask (only when mask has zeros — prescanned)
        if (anyz) {
#pragma unroll
          for (int j = 0; j < 4; j++)
#pragma unroll
            for (int r = 0; r < 4; r++) {
              float madd = (mp[s0 + j * 16 + g4 + r] == 0) ? -2e9f : 0.0f;
              S[0][j][r] += madd;
              S[1][j][r] += madd;
            }
        }
        // ---- causal edge: mask k > q
        if (s0 + 63 > qw0) {
#pragma unroll
          for (int j = 0; j < 4; j++) {
            int kk = s0 + j * 16 + g4;
#pragma unroll
            for (int r = 0; r < 4; r++) {
#pragma unroll
              for (int m = 0; m < 2; m++)
                if (kk + r > qw0 + m * 16 + c) S[m][j][r] = -1e30f;
            }
          }
        }

        // ---- tile max per q-row: lane-local 15 fmax + 2 shfl cross-g
        float tmax[2];
#pragma unroll
        for (int m = 0; m < 2; m++) {
          float t0 = fmaxf(fmaxf(S[m][0][0], S[m][0][1]), fmaxf(S[m][0][2], S[m][0][3]));
          float t1 = fmaxf(fmaxf(S[m][1][0], S[m][1][1]), fmaxf(S[m][1][2], S[m][1][3]));
          float t2 = fmaxf(fmaxf(S[m][2][0], S[m][2][1]), fmaxf(S[m][2][2], S[m][2][3]));
          float t3 = fmaxf(fmaxf(S[m][3][0], S[m][3][1]), fmaxf(S[m][3][2], S[m][3][3]));
          float t = fmaxf(fmaxf(t0, t1), fmaxf(t2, t3));
          t = fmaxf(t, __shfl_xor(t, 16));
          t = fmaxf(t, __shfl_xor(t, 32));
          tmax[m] = t;
        }
        // ---- defer-max (T13)
        bool upd = (tmax[0] > m_r[0] + 11.0f) || (tmax[1] > m_r[1] + 11.0f);
        if (__any(upd)) {
#pragma unroll
          for (int m = 0; m < 2; m++) {
            float mn = fmaxf(m_r[m], tmax[m]);
            float al = fexp2(m_r[m] - mn);
            m_r[m] = mn;
            l_r[m] *= al;
#pragma unroll
            for (int r = 0; r < 4; r++) {
              float alr = __shfl(al, (lane & 48) | (g4 + r));  // stats of q-row g*4+r
#pragma unroll
              for (int j2 = 0; j2 < 8; j2++) Oacc[m][j2][r] *= alr;
            }
          }
        }

        // ---- exp + per-lane l partial + P -> LDS (4-wide b64 writes, swizzled)
#pragma unroll
        for (int m = 0; m < 2; m++) {
          int rowb = (m * 16 + c) * 128;
#pragma unroll
          for (int j = 0; j < 4; j++) {
            float e0 = fexp2(S[m][j][0] - m_r[m]);
            float e1 = fexp2(S[m][j][1] - m_r[m]);
            float e2 = fexp2(S[m][j][2] - m_r[m]);
            float e3 = fexp2(S[m][j][3] - m_r[m]);
            l_r[m] += (e0 + e1) + (e2 + e3);
            uint2 w;
            w.x = pkbf(e0, e1);
            w.y = pkbf(e2, e3);
            int inrow = (j * 32 + g * 8) ^ c7s;
            *(uint2*)(PwB + rowb + inrow) = w;
          }
        }

        // ---- PV: O += P[32q x 64s] @ V^T  (pa frag: q=m*16+c, k=sk*32+g*8..+8)
        asm volatile("s_waitcnt lgkmcnt(0)" ::: "memory");
        bf16x8 pa[2][2];
#pragma unroll
        for (int m = 0; m < 2; m++)
#pragma unroll
          for (int sk = 0; sk < 2; sk++)
            pa[m][sk] = *(const bf16x8*)(PwB + (m * 16 + c) * 128 + (((sk * 64 + g * 16)) ^ c7s));
        __builtin_amdgcn_s_setprio(1);
#pragma unroll
        for (int sk = 0; sk < 2; sk++)
#pragma unroll
          for (int j2 = 0; j2 < 8; j2++) {
            int row = j2 * 16 + c;
            bf16x8 vfr = *(const bf16x8*)&Vc[row * 64 + (((sk * 4 + g) ^ (row & 7)) << 3)];
            Oacc[0][j2] = __builtin_amdgcn_mfma_f32_16x16x32_bf16(pa[0][sk], vfr, Oacc[0][j2], 0, 0, 0);
            Oacc[1][j2] = __builtin_amdgcn_mfma_f32_16x16x32_bf16(pa[1][sk], vfr, Oacc[1][j2], 0, 0, 0);
          }
        __builtin_amdgcn_s_setprio(0);
      }

      if (st + 1 < nt) {  // write next tile into the other buffer
        int nxt = cur ^ 1;
        *(bf16x8*)&Ks[nxt][kidx0] = krg[0];
        *(bf16x8*)&Ks[nxt][kidx1] = krg[1];
        *(bf16x8*)&Vs[nxt][vidx0] = vrg[0];
        *(bf16x8*)&Vs[nxt][vidx1] = vrg[1];
      }
      __syncthreads();  // one barrier per tile: next buf staged, cur reads done
    }

    // ---- epilogue: cross-g l reduce (per q-row), broadcast inv, store
#pragma unroll
    for (int m = 0; m < 2; m++) {
      float lt = l_r[m];
      lt += __shfl_xor(lt, 16);
      lt += __shfl_xor(lt, 32);
      float inv = 1.0f / lt;
#pragma unroll
      for (int r = 0; r < 4; r++) {
        float invr = __shfl(inv, (lane & 48) | (g4 + r));
        int qr = qw0 + m * 16 + g4 + r;
        unsigned short* ob = O + ((size_t)(b * Tc) + qr) * HIDc + h * Dc;
#pragma unroll
        for (int j2 = 0; j2 < 8; j2++) ob[j2 * 16 + c] = f2bfb(Oacc[m][j2][r] * invr);
      }
    }
  }
}

// ---------------- host launch ----------------

extern "C" void kernel_launch(void* const* d_in, const int* in_sizes, int n_in,
                              void* d_out, int out_size, void* d_ws, size_t ws_size,
                              hipStream_t stream) {
  const float* h = (const float*)d_in[0];
  const float* cg = (const float*)d_in[1];
  const float* sg = (const float*)d_in[2];
  const float* cl = (const float*)d_in[3];
  const float* sl = (const float*)d_in[4];
  const float* Wq_a = (const float*)d_in[5];
  const float* bq_a = (const float*)d_in[6];
  const float* Wq_b = (const float*)d_in[7];
  const float* bq_b = (const float*)d_in[8];
  const float* Wkv_a = (const float*)d_in[9];
  const float* bkv_a = (const float*)d_in[10];
  const float* Wkv_b = (const float*)d_in[11];
  const float* bkv_b = (const float*)d_in[12];
  const float* qw = (const float*)d_in[13];
  const float* kvw = (const float*)d_in[14];
  const float* Wo = (const float*)d_in[15];
  const float* nl = (const float*)d_in[16];
  const float* gl = (const float*)d_in[17];
  const int* am = (const int*)d_in[18];
  float* out = (float*)d_out;
  char* ws = (char*)d_ws;

  // ws layout (bytes); Obuf at 0
  const size_t o_hB = 0;             // bf16 [8192][2048]  33554432  (Obuf)
  const size_t o_Qf = 67108864;      // bf16 [B][H][T][D]  33554432
  const size_t o_A1 = 100663296;     // f32  [8192][256]    8388608
  const size_t o_Qn = 109051904;     // bf16 [8192][128]    2097152
  const size_t o_Kvn = 111149056;    // bf16 [8192][64]     1048576
  const size_t o_kvr = 112197632;    // bf16 [8192][256]    4194304
  const size_t o_Kf = 116391936;     // bf16 [8192][128]    2097152
  const size_t o_Vt = 118489088;     // bf16 [B*128][1024]  2097152
  const size_t o_W1t = 120586240;    // bf16 [256][2048]    1048576
  const size_t o_Wqbt = 121634816;   // bf16 [2048][128]     524288
  const size_t o_Wkbt = 122159104;   // bf16 [256][64]        32768
  const size_t o_Wot = 122191872;    // bf16 [2048][2048]   8388608
  const size_t o_cos = 130580480;    // f32  [65536]         262144
  const size_t o_sin = 130842624;    // f32  [65536]         262144

  unsigned short* Obuf = (unsigned short*)(ws + o_hB);
  unsigned short* Qf = (unsigned short*)(ws + o_Qf);
  float* A1 = (float*)(ws + o_A1);
  unsigned short* Qn = (unsigned short*)(ws + o_Qn);
  unsigned short* Kvn = (unsigned short*)(ws + o_Kvn);
  unsigned short* kvr = (unsigned short*)(ws + o_kvr);
  unsigned short* Kf = (unsigned short*)(ws + o_Kf);
  unsigned short* Vt = (unsigned short*)(ws + o_Vt);
  unsigned short* W1t = (unsigned short*)(ws + o_W1t);
  unsigned short* Wqbt = (unsigned short*)(ws + o_Wqbt);
  unsigned short* Wkbt = (unsigned short*)(ws + o_Wkbt);
  unsigned short* Wot = (unsigned short*)(ws + o_Wot);
  float* cosb = (float*)(ws + o_cos);
  float* sinb = (float*)(ws + o_sin);

  (void)in_sizes; (void)n_in; (void)out_size; (void)ws_size;

  // prep
  k_blend<<<256, 256, 0, stream>>>(cg, sg, cl, sl, gl, cosb, sinb);
  k_zero<<<512, 256, 0, stream>>>(W1t + (size_t)192 * 2048, 64 * 2048);
  k_transpose<<<dim3(4, 64), 256, 0, stream>>>(Wq_a, W1t, 2048, 128);
  k_transpose<<<dim3(2, 64), 256, 0, stream>>>(Wkv_a, W1t + (size_t)128 * 2048, 2048, 64);
  k_transpose<<<dim3(64, 4), 256, 0, stream>>>(Wq_b, Wqbt, 128, 2048);
  k_transpose<<<dim3(8, 2), 256, 0, stream>>>(Wkv_b, Wkbt, 64, 256);
  k_transpose<<<dim3(64, 64), 256, 0, stream>>>(Wo, Wot, 2048, 2048);

  // GEMM1 (fused f32->bf16 A): [8192,2048]@[2048,256] -> fp32  (grid 256)
  k_gemm1<<<256, 256, 0, stream>>>(h, W1t, A1);
  // split rmsnorm
  k_norm<<<2048, 256, 0, stream>>>(A1, bq_a, bkv_a, qw, kvw, Qn, Kvn);
  // GEMM2a + fused RoPE-Q: [8192,128]@[128,2048] -> Qf  (grid 1024 = 64x16)
  k_gemm2q<<<1024, 256, 0, stream>>>(Qn, Wqbt, bq_b, cosb, sinb, nl, Qf);
  // GEMM2b: [8192,64]@[64,256] -> bf16      (grid 128 = 2x64)
  k_gemm<1><<<128, 256, 0, stream>>>(Kvn, Wkbt, kvr, ROWSc, 256, 64, 2);
  // rope + mix for K/V
  k_rope_kv<<<2048, 256, 0, stream>>>(kvr, bkv_b, cosb, sinb, nl, Kf, Vt);
  // attention: 256 blocks (h*16 + pair*8 + b) x 512 threads (swapped-QK R11)
  k_attn<<<256, 512, 0, stream>>>(Qf, Kf, Vt, am, Obuf);
  // GEMM3: [8192,2048]@[2048,2048] -> fp32 out  (grid 1024 = 16x64)
  k_gemm<0><<<1024, 256, 0, stream>>>(Obuf, Wot, out, ROWSc, HIDc, 2048, 16);
}